// Round 1
// 347.106 us; speedup vs baseline: 1.0603x; 1.0603x over previous
//
#include <hip/hip_runtime.h>
#include <hip/hip_bf16.h>

// y = x @ P,  P = gamma * (w_q w_k^T) (x^T x) w_v      (no softmax => associativity)
// All GEMMs in one "NT" form: C[m][n] = scale * sum_k A[m][k] * B[n][k]
//
// This revision ports the two measured MI355X ladder steps (m93+m97):
//   - 128x128 (and 64x128) tiles, 4 waves, 16 (resp. 8) MFMA per K-step per wave
//   - global_load_lds width-16 async staging into LINEAR [rows][32] LDS tiles
// plus split-K for G (occupancy: 256 -> 512 blocks) and 64x128 tiles for the
// D^3 chain GEMMs (1 -> 2 blocks/CU).

typedef __attribute__((ext_vector_type(8))) short bf16x8;   // 8 x bf16 (4 VGPRs)
typedef __attribute__((ext_vector_type(4))) float f32x4;    // 4 x fp32 accum

// async global->LDS, 16B per lane. LDS dest is wave-uniform base + lane*16
// (hardware semantics), so we pass per-lane lds ptrs that are exactly that.
__device__ __forceinline__ void gload16(const void* g, void* l) {
    __builtin_amdgcn_global_load_lds((__attribute__((address_space(1))) void*)g,
                                     (__attribute__((address_space(3))) void*)l,
                                     16, 0, 0);
}

// TM x TN block tile, BK=32, 256 threads (4 waves in 2x2), per-wave (TM/2)x(TN/2).
// blockIdx.z encodes (k-chunk, batch): batch = z % nb, kchunk = z / nb.
// A/B element offset: batch*sA + (m0+row)*ldA + kchunk*Kc + k.  C offset: z*sC.
template<int TM, int TN, bool A_F32, bool OUT_F32>
__global__ __launch_bounds__(256)
void gemm_nt(const void* __restrict__ Ap, const __hip_bfloat16* __restrict__ Bp,
             void* __restrict__ Cp, int N, int Kc, int ldA, int ldB,
             long sA, long sB, long sC, int nb, float scale)
{
    constexpr int FM = TM / 32;   // 16x16 fragment rows per wave
    constexpr int FN = TN / 32;

    __shared__ __hip_bfloat16 At[TM][32];   // linear: global_load_lds needs no pad
    __shared__ __hip_bfloat16 Bt[TN][32];

    const int bz    = blockIdx.z;
    const int batch = bz % nb;
    const int kc    = bz / nb;
    const int n0 = blockIdx.x * TN;
    const int m0 = blockIdx.y * TM;

    const int tid  = threadIdx.x;
    const int lane = tid & 63;
    const int wave = tid >> 6;
    const int wm = (wave & 1) * (TM / 2);
    const int wn = (wave >> 1) * (TN / 2);
    const int l16 = lane & 15;
    const int lq  = lane >> 4;        // 0..3

    // staging: per wave, instr i fills a contiguous 1KB LDS stripe.
    // elem offset = wave*(T_*8) + i*512 + lane*8 ; row = off/32, col = off%32
    const int aoff = wave * (TM * 8) + lane * 8;
    const int boff = wave * (TN * 8) + lane * 8;

    const __hip_bfloat16* Bb = Bp + (size_t)batch * sB + (size_t)kc * Kc;

    f32x4 acc[FM][FN];
    #pragma unroll
    for (int i = 0; i < FM; ++i)
        #pragma unroll
        for (int j = 0; j < FN; ++j)
            acc[i][j] = (f32x4){0.f, 0.f, 0.f, 0.f};

    for (int k0 = 0; k0 < Kc; k0 += 32) {
        if constexpr (A_F32) {
            // reg-staged fp32 -> bf16 (x cannot be pre-cast without racing d_out)
            const float* Ab = (const float*)Ap + (size_t)batch * sA + (size_t)kc * Kc;
            const int r  = tid >> 1;
            const int cb = (tid & 1) * 16;
            const float* s = Ab + (size_t)(m0 + r) * ldA + k0 + cb;
            float4 f0 = *(const float4*)(s);
            float4 f1 = *(const float4*)(s + 4);
            float4 f2 = *(const float4*)(s + 8);
            float4 f3 = *(const float4*)(s + 12);
            union { __hip_bfloat16 h[8]; uint4 u; } t0, t1;
            t0.h[0] = __float2bfloat16(f0.x); t0.h[1] = __float2bfloat16(f0.y);
            t0.h[2] = __float2bfloat16(f0.z); t0.h[3] = __float2bfloat16(f0.w);
            t0.h[4] = __float2bfloat16(f1.x); t0.h[5] = __float2bfloat16(f1.y);
            t0.h[6] = __float2bfloat16(f1.z); t0.h[7] = __float2bfloat16(f1.w);
            t1.h[0] = __float2bfloat16(f2.x); t1.h[1] = __float2bfloat16(f2.y);
            t1.h[2] = __float2bfloat16(f2.z); t1.h[3] = __float2bfloat16(f2.w);
            t1.h[4] = __float2bfloat16(f3.x); t1.h[5] = __float2bfloat16(f3.y);
            t1.h[6] = __float2bfloat16(f3.z); t1.h[7] = __float2bfloat16(f3.w);
            *(uint4*)&At[r][cb]     = t0.u;
            *(uint4*)&At[r][cb + 8] = t1.u;
        } else {
            const __hip_bfloat16* Ab =
                (const __hip_bfloat16*)Ap + (size_t)batch * sA + (size_t)kc * Kc;
            #pragma unroll
            for (int i = 0; i < TM / 64; ++i) {
                const __hip_bfloat16* s =
                    Ab + (size_t)(m0 + (aoff >> 5) + i * 16) * ldA + k0 + (aoff & 31);
                gload16(s, (__hip_bfloat16*)At + aoff + i * 512);
            }
        }
        #pragma unroll
        for (int i = 0; i < TN / 64; ++i) {
            const __hip_bfloat16* s =
                Bb + (size_t)(n0 + (boff >> 5) + i * 16) * ldB + k0 + (boff & 31);
            gload16(s, (__hip_bfloat16*)Bt + boff + i * 512);
        }
        __syncthreads();   // compiler drains vmcnt+lgkm here

        // fragments: A[m=lane&15][k=(lane>>4)*8+j], B mirrored (harness-verified)
        bf16x8 av[FM], bv[FN];
        #pragma unroll
        for (int i = 0; i < FM; ++i)
            av[i] = *(const bf16x8*)&At[wm + i * 16 + l16][lq * 8];
        #pragma unroll
        for (int j = 0; j < FN; ++j)
            bv[j] = *(const bf16x8*)&Bt[wn + j * 16 + l16][lq * 8];
        #pragma unroll
        for (int i = 0; i < FM; ++i)
            #pragma unroll
            for (int j = 0; j < FN; ++j)
                acc[i][j] = __builtin_amdgcn_mfma_f32_16x16x32_bf16(av[i], bv[j], acc[i][j], 0, 0, 0);
        __syncthreads();
    }

    // epilogue: C/D layout col=lane&15, row=(lane>>4)*4+reg (m89/m91-verified)
    float* Cf = (float*)Cp;
    __hip_bfloat16* Ch = (__hip_bfloat16*)Cp;
    const size_t cb0 = (size_t)bz * sC;
    #pragma unroll
    for (int i = 0; i < FM; ++i) {
        #pragma unroll
        for (int j = 0; j < FN; ++j) {
            const int row0 = m0 + wm + i * 16 + lq * 4;
            const int col  = n0 + wn + j * 16 + l16;
            #pragma unroll
            for (int r = 0; r < 4; ++r) {
                float v = acc[i][j][r] * scale;
                size_t idx = cb0 + (size_t)(row0 + r) * N + col;
                if (OUT_F32) Cf[idx] = v;
                else         Ch[idx] = __float2bfloat16(v);
            }
        }
    }
}

// Gb[b] = bf16( Gpart[b] + Gpart[4+b] )   (split-K=2 fp32 partial reduce)
// part layout: (kchunk*4 + b)*DD + j ; out layout: b*DD + j == linear l. DD = 1<<20.
__global__ __launch_bounds__(256)
void reduce_kchunks(const float* __restrict__ part, __hip_bfloat16* __restrict__ out)
{
    const size_t l = ((size_t)blockIdx.x * 256 + threadIdx.x) * 4;
    float4 a = *(const float4*)&part[l];
    float4 c = *(const float4*)&part[l + ((size_t)4 << 20)];
    union { __hip_bfloat16 h[4]; uint2 u; } t;
    t.h[0] = __float2bfloat16(a.x + c.x);
    t.h[1] = __float2bfloat16(a.y + c.y);
    t.h[2] = __float2bfloat16(a.z + c.z);
    t.h[3] = __float2bfloat16(a.w + c.w);
    *(uint2*)&out[l] = t.u;
}

// Tiled transpose + fp32->bf16 cast: in (R x C) fp32 row-major -> out (C x R) bf16.
// v2: float4 loads, transposed LDS writes, uint2 (4x bf16) stores.
#define TP 64
__global__ __launch_bounds__(256)
void transpose_cast(const float* __restrict__ in, __hip_bfloat16* __restrict__ out,
                    int R, int C, long inStride, long outStride)
{
    __shared__ __hip_bfloat16 t2[TP][TP + 4];   // pitch 68: keeps 8B-aligned row reads
    const int b  = blockIdx.z;
    const int r0 = blockIdx.x * TP;
    const int c0 = blockIdx.y * TP;
    const float* inb = in + (size_t)b * inStride;
    __hip_bfloat16* outb = out + (size_t)b * outStride;
    const int t  = threadIdx.x;       // 0..255
    const int rr = t >> 4;            // 0..15
    const int c4 = (t & 15) * 4;
    #pragma unroll
    for (int p = 0; p < 4; ++p) {
        const int row = p * 16 + rr;
        float4 f = *(const float4*)&inb[(size_t)(r0 + row) * C + c0 + c4];
        t2[c4 + 0][row] = __float2bfloat16(f.x);
        t2[c4 + 1][row] = __float2bfloat16(f.y);
        t2[c4 + 2][row] = __float2bfloat16(f.z);
        t2[c4 + 3][row] = __float2bfloat16(f.w);
    }
    __syncthreads();
    #pragma unroll
    for (int p = 0; p < 4; ++p) {
        const int crow = p * 16 + rr;     // output row = input column c0+crow
        union { __hip_bfloat16 h[4]; uint2 u; } o;
        #pragma unroll
        for (int j = 0; j < 4; ++j) o.h[j] = t2[crow][c4 + j];
        *(uint2*)&outb[(size_t)(c0 + crow) * R + r0 + c4] = o.u;
    }
}

__global__ __launch_bounds__(256)
void cast_f32_bf16(const float* __restrict__ in, __hip_bfloat16* __restrict__ out, int n)
{
    const int i = (blockIdx.x * 256 + threadIdx.x) << 2;
    if (i >= n) return;
    float4 f = *(const float4*)(in + i);
    union { __hip_bfloat16 h[4]; uint2 u; } t;
    t.h[0] = __float2bfloat16(f.x); t.h[1] = __float2bfloat16(f.y);
    t.h[2] = __float2bfloat16(f.z); t.h[3] = __float2bfloat16(f.w);
    *(uint2*)(out + i) = t.u;
}

extern "C" void kernel_launch(void* const* d_in, const int* in_sizes, int n_in,
                              void* d_out, int out_size, void* d_ws, size_t ws_size,
                              hipStream_t stream)
{
    const int Bz = 4, T = 4096, D = 1024;
    const float gamma = 32.0f;  // sqrt(1024)

    const float* x  = (const float*)d_in[0];
    const float* wq = (const float*)d_in[1];
    const float* wk = (const float*)d_in[2];
    const float* wv = (const float*)d_in[3];
    float* y = (float*)d_out;

    // workspace layout (32 MB total)
    unsigned char* p = (unsigned char*)d_ws;
    const size_t DD = (size_t)D * D;
    __hip_bfloat16* Gb  = (__hip_bfloat16*)p; p += Bz * DD * 2;   //  8 MB  G_b = x_b^T x_b
    __hip_bfloat16* Hb  = (__hip_bfloat16*)p; p += Bz * DD * 2;   //  8 MB  H_b = C0 G_b
    __hip_bfloat16* PTb = (__hip_bfloat16*)p; p += Bz * DD * 2;   //  8 MB  P_b^T
    __hip_bfloat16* wqb = (__hip_bfloat16*)p; p += DD * 2;        //  2 MB
    __hip_bfloat16* wkb = (__hip_bfloat16*)p; p += DD * 2;        //  2 MB
    __hip_bfloat16* wvT = (__hip_bfloat16*)p; p += DD * 2;        //  2 MB  w_v^T
    __hip_bfloat16* C0b = (__hip_bfloat16*)p; p += DD * 2;        //  2 MB  w_q w_k^T
    // d_out (64 MB) staging: xbT bf16 in [0,32MB); G split-K fp32 partials in
    // [32,64MB). Both dead before the final y GEMM rewrites all of d_out.
    __hip_bfloat16* xbT = (__hip_bfloat16*)d_out;
    float* Gpart = (float*)((unsigned char*)d_out + (size_t)32 * 1024 * 1024);

    dim3 blk(256);

    // casts / transposes
    cast_f32_bf16<<<dim3((int)(DD / 1024)), blk, 0, stream>>>(wq, wqb, (int)DD);
    cast_f32_bf16<<<dim3((int)(DD / 1024)), blk, 0, stream>>>(wk, wkb, (int)DD);
    transpose_cast<<<dim3(D / TP, D / TP, 1), blk, 0, stream>>>(wv, wvT, D, D, 0, 0);
    transpose_cast<<<dim3(T / TP, D / TP, Bz), blk, 0, stream>>>(
        x, xbT, T, D, (long)T * D, (long)D * T);

    // C0 = w_q w_k^T                      : NT(A=wq, B=wk)          64x128 tile
    gemm_nt<64, 128, false, false><<<dim3(D / 128, D / 64, 1), blk, 0, stream>>>(
        wqb, wkb, C0b, D, D, D, D, 0, 0, 0, 1, 1.0f);
    // Gpart[c,b] = xbT[b][:, c*2048:+2048] x same  : split-K=2, fp32 partials
    gemm_nt<128, 128, false, true><<<dim3(D / 128, D / 128, 2 * Bz), blk, 0, stream>>>(
        xbT, xbT, Gpart, D, T / 2, T, T, (long)D * T, (long)D * T, (long)DD, Bz, 1.0f);
    // Gb = bf16(Gpart[0] + Gpart[1])
    reduce_kchunks<<<dim3((int)(Bz * DD / 1024)), blk, 0, stream>>>(Gpart, Gb);
    // H_b = C0 G_b  (G symmetric)         : NT(A=C0, B=G)           64x128 tile
    gemm_nt<64, 128, false, false><<<dim3(D / 128, D / 64, Bz), blk, 0, stream>>>(
        C0b, Gb, Hb, D, D, D, D, 0, (long)DD, (long)DD, Bz, 1.0f);
    // P_b^T = gamma * w_v^T H_b^T         : NT(A=wvT, B=H)          64x128 tile
    gemm_nt<64, 128, false, false><<<dim3(D / 128, D / 64, Bz), blk, 0, stream>>>(
        wvT, Hb, PTb, D, D, D, D, 0, (long)DD, (long)DD, Bz, gamma);
    // y_b = x_b P_b                       : NT(A=x fp32, B=P^T)     128x128 tile
    gemm_nt<128, 128, true, true><<<dim3(D / 128, T / 128, Bz), blk, 0, stream>>>(
        x, PTb, y, D, D, D, D, (long)T * D, (long)DD, (long)T * D, Bz, 1.0f);
}

// Round 3
// 326.108 us; speedup vs baseline: 1.1286x; 1.0644x over previous
//
#include <hip/hip_runtime.h>
#include <hip/hip_bf16.h>

// y = x @ P,  P = gamma * (w_q w_k^T) (x^T x) w_v      (no softmax => associativity)
// All GEMMs: NT form  C[m][n] = scale * sum_k A[m][k] * B[n][k], all operands bf16,
// staged with global_load_lds width-16 (m97 structure), T1 XCD-swizzled grids.
//
// Buffer choreography (stream-ordered dispatches; no intra-dispatch overlap):
//   d_out[ 0,32M): xbT   (bf16 x^T, per batch D x T)     dead after G GEMM
//   d_out[32,48M): xb01  (bf16 x rows, batches 0,1)      dead after y-dispatch-A
//   ws: Gb | Hb | PTb | wqb wkb wvT C0b
//   G split-K partials (bf16, 16M) live in Hb+PTb slots  dead after reduce
//   xb23 (bf16 x rows, batches 2,3) lives in Gb+Hb slots (cast after P GEMM)
//   y-dispatch-A writes d_out[0,32M); y-dispatch-B writes d_out[32,64M).

typedef __attribute__((ext_vector_type(8))) short bf16x8;   // 8 x bf16 (4 VGPRs)
typedef __attribute__((ext_vector_type(4))) float f32x4;    // 4 x fp32 accum

__device__ __forceinline__ unsigned short bf16bits(float f) {
    union { __hip_bfloat16 b; unsigned short s; } r;
    r.b = __float2bfloat16(f);
    return r.s;
}

// async global->LDS, 16B per lane; LDS dest must be wave-uniform base + lane*16.
__device__ __forceinline__ void gload16(const void* g, void* l) {
    __builtin_amdgcn_global_load_lds((__attribute__((address_space(1))) void*)g,
                                     (__attribute__((address_space(3))) void*)l,
                                     16, 0, 0);
}

// TM x TN block tile, BK=32, 256 threads (4 waves 2x2), per-wave (TM/2)x(TN/2).
// blockIdx.z = kchunk*nb + batch. Operand offset: batch*s + row*ld + kchunk*Kc + k.
template<int TM, int TN, bool OUT_F32>
__global__ __launch_bounds__(256)
void gemm_nt(const __hip_bfloat16* __restrict__ Ap, const __hip_bfloat16* __restrict__ Bp,
             void* __restrict__ Cp, int N, int Kc, int ldA, int ldB,
             long sA, long sB, long sC, int nb, float scale)
{
    constexpr int FM = TM / 32;   // 16x16 fragment rows per wave
    constexpr int FN = TN / 32;

    __shared__ __hip_bfloat16 At[TM][32];   // linear: global_load_lds dest, no pad
    __shared__ __hip_bfloat16 Bt[TN][32];

    const int bz    = blockIdx.z;
    const int batch = bz % nb;
    const int kc    = bz / nb;

    // T1: bijective XCD-chunked swizzle (all per-slice grids here are %8==0).
    // Hardware block h on XCD h%8 computes tile (h%8)*cpx + h/8 -> each XCD owns a
    // contiguous row-major tile range -> A-panels fetched once per XCD L2.
    int wg = blockIdx.y * gridDim.x + blockIdx.x;
    const int cpx = (int)(gridDim.x * gridDim.y) >> 3;
    wg = (wg & 7) * cpx + (wg >> 3);
    const int n0 = (wg % (int)gridDim.x) * TN;
    const int m0 = (wg / (int)gridDim.x) * TM;

    const int tid  = threadIdx.x;
    const int lane = tid & 63;
    const int wave = tid >> 6;
    const int wm = (wave & 1) * (TM / 2);
    const int wn = (wave >> 1) * (TN / 2);
    const int l16 = lane & 15;
    const int lq  = lane >> 4;        // 0..3

    // staging: per wave, instr i fills a contiguous 1KB LDS stripe.
    const int aoff = wave * (TM * 8) + lane * 8;
    const int boff = wave * (TN * 8) + lane * 8;

    const __hip_bfloat16* Ab = Ap + (size_t)batch * sA + (size_t)kc * Kc;
    const __hip_bfloat16* Bb = Bp + (size_t)batch * sB + (size_t)kc * Kc;

    f32x4 acc[FM][FN];
    #pragma unroll
    for (int i = 0; i < FM; ++i)
        #pragma unroll
        for (int j = 0; j < FN; ++j)
            acc[i][j] = (f32x4){0.f, 0.f, 0.f, 0.f};

    for (int k0 = 0; k0 < Kc; k0 += 32) {
        #pragma unroll
        for (int i = 0; i < TM / 64; ++i) {
            const __hip_bfloat16* s =
                Ab + (size_t)(m0 + (aoff >> 5) + i * 16) * ldA + k0 + (aoff & 31);
            gload16(s, (__hip_bfloat16*)At + aoff + i * 512);
        }
        #pragma unroll
        for (int i = 0; i < TN / 64; ++i) {
            const __hip_bfloat16* s =
                Bb + (size_t)(n0 + (boff >> 5) + i * 16) * ldB + k0 + (boff & 31);
            gload16(s, (__hip_bfloat16*)Bt + boff + i * 512);
        }
        __syncthreads();   // compiler drains vmcnt+lgkm here

        // fragments: A[m=lane&15][k=(lane>>4)*8+j], B mirrored (harness-verified)
        bf16x8 av[FM], bv[FN];
        #pragma unroll
        for (int i = 0; i < FM; ++i)
            av[i] = *(const bf16x8*)&At[wm + i * 16 + l16][lq * 8];
        #pragma unroll
        for (int j = 0; j < FN; ++j)
            bv[j] = *(const bf16x8*)&Bt[wn + j * 16 + l16][lq * 8];
        #pragma unroll
        for (int i = 0; i < FM; ++i)
            #pragma unroll
            for (int j = 0; j < FN; ++j)
                acc[i][j] = __builtin_amdgcn_mfma_f32_16x16x32_bf16(av[i], bv[j], acc[i][j], 0, 0, 0);
        __syncthreads();
    }

    // epilogue: C/D layout col=lane&15, row=(lane>>4)*4+reg (m89/m91-verified)
    float* Cf = (float*)Cp;
    __hip_bfloat16* Ch = (__hip_bfloat16*)Cp;
    const size_t cb0 = (size_t)bz * sC;
    #pragma unroll
    for (int i = 0; i < FM; ++i) {
        #pragma unroll
        for (int j = 0; j < FN; ++j) {
            const int row0 = m0 + wm + i * 16 + lq * 4;
            const int col  = n0 + wn + j * 16 + l16;
            #pragma unroll
            for (int r = 0; r < 4; ++r) {
                float v = acc[i][j][r] * scale;
                size_t idx = cb0 + (size_t)(row0 + r) * N + col;
                if (OUT_F32) Cf[idx] = v;
                else         Ch[idx] = __float2bfloat16(v);
            }
        }
    }
}

// Gb[b] = bf16( Gpart[b] + Gpart[4+b] ), bf16 partials, 8 elems/thread.
__global__ __launch_bounds__(256)
void reduce_kchunks(const unsigned short* __restrict__ part,
                    unsigned short* __restrict__ out)
{
    const size_t l = ((size_t)blockIdx.x * 256 + threadIdx.x) * 8;
    const size_t DD4 = (size_t)4 << 20;   // 4 * D * D elements
    union { unsigned short h[8]; uint4 u; } a, b, o;
    a.u = *(const uint4*)(part + l);
    b.u = *(const uint4*)(part + l + DD4);
    #pragma unroll
    for (int j = 0; j < 8; ++j) {
        union { float f; unsigned int u; } fa, fb;
        fa.u = (unsigned int)a.h[j] << 16;
        fb.u = (unsigned int)b.h[j] << 16;
        o.h[j] = bf16bits(fa.f + fb.f);
    }
    *(uint4*)(out + l) = o.u;
}

// Tiled transpose + fp32->bf16 cast: in (R x C) fp32 row-major -> out (C x R) bf16.
// Batches b < nsb additionally emit a straight row-major bf16 copy (fused cast).
#define TP 64
__global__ __launch_bounds__(256)
void transpose_cast(const float* __restrict__ in, __hip_bfloat16* __restrict__ out,
                    __hip_bfloat16* __restrict__ straight, int nsb,
                    int R, int C, long inStride, long outStride)
{
    __shared__ __hip_bfloat16 t2[TP][TP + 4];   // pitch 68: 8B-aligned row reads
    const int b  = blockIdx.z;
    const int r0 = blockIdx.x * TP;
    const int c0 = blockIdx.y * TP;
    const float* inb = in + (size_t)b * inStride;
    __hip_bfloat16* outb = out + (size_t)b * outStride;
    __hip_bfloat16* stb  = straight + (size_t)b * inStride;   // same shape as input
    const int t  = threadIdx.x;       // 0..255
    const int rr = t >> 4;            // 0..15
    const int c4 = (t & 15) * 4;
    #pragma unroll
    for (int p = 0; p < 4; ++p) {
        const int row = p * 16 + rr;
        float4 f = *(const float4*)&inb[(size_t)(r0 + row) * C + c0 + c4];
        union { __hip_bfloat16 h[4]; uint2 u; } s;
        s.h[0] = __float2bfloat16(f.x); s.h[1] = __float2bfloat16(f.y);
        s.h[2] = __float2bfloat16(f.z); s.h[3] = __float2bfloat16(f.w);
        t2[c4 + 0][row] = s.h[0];
        t2[c4 + 1][row] = s.h[1];
        t2[c4 + 2][row] = s.h[2];
        t2[c4 + 3][row] = s.h[3];
        if (b < nsb)
            *(uint2*)&stb[(size_t)(r0 + row) * C + c0 + c4] = s.u;
    }
    __syncthreads();
    #pragma unroll
    for (int p = 0; p < 4; ++p) {
        const int crow = p * 16 + rr;     // output row = input column c0+crow
        union { __hip_bfloat16 h[4]; uint2 u; } o;
        #pragma unroll
        for (int j = 0; j < 4; ++j) o.h[j] = t2[crow][c4 + j];
        *(uint2*)&outb[(size_t)(c0 + crow) * R + r0 + c4] = o.u;
    }
}

__global__ __launch_bounds__(256)
void cast_f32_bf16(const float* __restrict__ in, __hip_bfloat16* __restrict__ out, int n)
{
    const int i = (blockIdx.x * 256 + threadIdx.x) << 2;
    if (i >= n) return;
    float4 f = *(const float4*)(in + i);
    union { __hip_bfloat16 h[4]; uint2 u; } t;
    t.h[0] = __float2bfloat16(f.x); t.h[1] = __float2bfloat16(f.y);
    t.h[2] = __float2bfloat16(f.z); t.h[3] = __float2bfloat16(f.w);
    *(uint2*)(out + i) = t.u;
}

extern "C" void kernel_launch(void* const* d_in, const int* in_sizes, int n_in,
                              void* d_out, int out_size, void* d_ws, size_t ws_size,
                              hipStream_t stream)
{
    const int Bz = 4, T = 4096, D = 1024;
    const float gamma = 32.0f;  // sqrt(1024)

    const float* x  = (const float*)d_in[0];
    const float* wq = (const float*)d_in[1];
    const float* wk = (const float*)d_in[2];
    const float* wv = (const float*)d_in[3];
    float* y = (float*)d_out;

    // workspace layout (32 MB total)
    unsigned char* p = (unsigned char*)d_ws;
    const size_t DD = (size_t)D * D;
    __hip_bfloat16* Gb  = (__hip_bfloat16*)p; p += Bz * DD * 2;   //  8 MB
    __hip_bfloat16* Hb  = (__hip_bfloat16*)p; p += Bz * DD * 2;   //  8 MB
    __hip_bfloat16* PTb = (__hip_bfloat16*)p; p += Bz * DD * 2;   //  8 MB
    __hip_bfloat16* wqb = (__hip_bfloat16*)p; p += DD * 2;        //  2 MB
    __hip_bfloat16* wkb = (__hip_bfloat16*)p; p += DD * 2;        //  2 MB
    __hip_bfloat16* wvT = (__hip_bfloat16*)p; p += DD * 2;        //  2 MB
    __hip_bfloat16* C0b = (__hip_bfloat16*)p; p += DD * 2;        //  2 MB
    __hip_bfloat16* Gpart = Hb;                                   // 16 MB (Hb+PTb), dead after reduce
    __hip_bfloat16* xb23  = Gb;                                   // 16 MB (Gb+Hb), written after P GEMM

    __hip_bfloat16* xbT  = (__hip_bfloat16*)d_out;                                  // [0,32M)
    __hip_bfloat16* xb01 = (__hip_bfloat16*)((unsigned char*)d_out + ((size_t)32 << 20)); // [32,48M)

    dim3 blk(256);

    // weight casts / transposes; x transpose fuses the bf16 row-major copy of b0,b1
    cast_f32_bf16<<<dim3((int)(DD / 1024)), blk, 0, stream>>>(wq, wqb, (int)DD);
    cast_f32_bf16<<<dim3((int)(DD / 1024)), blk, 0, stream>>>(wk, wkb, (int)DD);
    transpose_cast<<<dim3(D / TP, D / TP, 1), blk, 0, stream>>>(
        wv, wvT, wvT, 0, D, D, 0, 0);
    transpose_cast<<<dim3(T / TP, D / TP, Bz), blk, 0, stream>>>(
        x, xbT, xb01, 2, T, D, (long)T * D, (long)D * T);

    // C0 = w_q w_k^T                      : NT(wq, wk)             64x128 tile
    gemm_nt<64, 128, false><<<dim3(D / 128, D / 64, 1), blk, 0, stream>>>(
        wqb, wkb, C0b, D, D, D, D, 0, 0, 0, 1, 1.0f);
    // Gpart[kc*4+b] = xbT[b][:, kc*2048:+2048] x same : split-K=2, bf16 partials
    gemm_nt<128, 128, false><<<dim3(D / 128, D / 128, 2 * Bz), blk, 0, stream>>>(
        xbT, xbT, Gpart, D, T / 2, T, T, (long)D * T, (long)D * T, (long)DD, Bz, 1.0f);
    // Gb = bf16(Gpart[b] + Gpart[4+b])
    reduce_kchunks<<<dim3((int)(Bz * DD / 2048)), blk, 0, stream>>>(
        (const unsigned short*)Gpart, (unsigned short*)Gb);
    // H_b = C0 G_b (G symmetric)          : NT(C0, G)              64x128 tile
    gemm_nt<64, 128, false><<<dim3(D / 128, D / 64, Bz), blk, 0, stream>>>(
        C0b, Gb, Hb, D, D, D, D, 0, (long)DD, (long)DD, Bz, 1.0f);
    // P_b^T = gamma * w_v^T H_b^T         : NT(wvT, H)             64x128 tile
    gemm_nt<64, 128, false><<<dim3(D / 128, D / 64, Bz), blk, 0, stream>>>(
        wvT, Hb, PTb, D, D, D, D, 0, (long)DD, (long)DD, Bz, gamma);

    // xb23 = bf16(x[b2,b3]) into dead Gb+Hb slots (stream-ordered after P GEMM)
    cast_f32_bf16<<<dim3((int)(2 * (size_t)T * D / 1024)), blk, 0, stream>>>(
        x + (size_t)2 * T * D, xb23, (int)(2 * (size_t)T * D));

    // y_b = x_b P_b : NT(xb, P^T), fp32 out, two dispatches for buffer liveness
    // A: batches 0,1 read xb01 @ d_out[32,48M), write y @ d_out[0,32M)
    gemm_nt<128, 128, true><<<dim3(D / 128, T / 128, 2), blk, 0, stream>>>(
        xb01, PTb, y, D, D, D, D, (long)T * D, (long)DD, (long)T * D, 2, 1.0f);
    // B: batches 2,3 read xb23 @ ws, write y @ d_out[32,64M) (xb01 dead)
    gemm_nt<128, 128, true><<<dim3(D / 128, T / 128, 2), blk, 0, stream>>>(
        xb23, PTb + 2 * DD, y + (size_t)2 * T * D, D, D, D, D,
        (long)T * D, (long)DD, (long)T * D, 2, 1.0f);
}

// Round 4
// 297.277 us; speedup vs baseline: 1.2381x; 1.0970x over previous
//
#include <hip/hip_runtime.h>
#include <hip/hip_bf16.h>

// y = x @ P,  P = gamma * (w_q w_k^T) (x^T x) w_v      (no softmax => associativity)
// All GEMMs: NT form  C[m][n] = scale * sum_k A[m][k] * B[n][k], all operands bf16,
// global_load_lds width-16 staging, double-buffered LDS (1 barrier / K-step),
// XCD-pinned block scheduling (MODE 1: slice->XCD, MODE 2: batch->XCD).
//
// Buffer choreography (stream-ordered dispatches):
//   d_out[ 0,32M): xbT   (bf16 x^T, per batch D x T)     dead after G GEMM
//   d_out[32,48M): xb01  (bf16 x rows, batches 0,1)      dead after y-dispatch-A
//   ws: Gb | Hb | PTb | wqb wkb wvT C0b
//   G split-K partials (bf16, 16M) live in Hb+PTb slots  dead after reduce
//   xb23 (bf16 x rows, batches 2,3) lives in Gb+Hb slots (cast after P GEMM)
//   y-dispatch-A writes d_out[0,32M); y-dispatch-B writes d_out[32,64M).

typedef __attribute__((ext_vector_type(8))) short bf16x8;   // 8 x bf16 (4 VGPRs)
typedef __attribute__((ext_vector_type(4))) float f32x4;    // 4 x fp32 accum

__device__ __forceinline__ unsigned short bf16bits(float f) {
    union { __hip_bfloat16 b; unsigned short s; } r;
    r.b = __float2bfloat16(f);
    return r.s;
}

// async global->LDS, 16B per lane; LDS dest must be wave-uniform base + lane*16.
__device__ __forceinline__ void gload16(const void* g, void* l) {
    __builtin_amdgcn_global_load_lds((__attribute__((address_space(1))) void*)g,
                                     (__attribute__((address_space(3))) void*)l,
                                     16, 0, 0);
}

// TM x TN block tile, BK=32, 256 threads (4 waves 2x2), per-wave (TM/2)x(TN/2).
// Block scheduling by MODE (h = hardware linear block id, XCD ~ h%8):
//   MODE 0: slice = blockIdx.z; chunked (x,y) swizzle (8-XCD m-row chunks).
//   MODE 1: slice-pinned. gz % 8 == 0. Each XCD owns gz/8 whole slices ->
//           slice's operand panels stay resident in that XCD's L2.
//   MODE 2: batch-pinned. gz = nb (<=8, divides 8). XCD serves one batch;
//           8/nb XCDs per batch, each owning a contiguous m-row tile chunk.
// Operand offset: batch*s + row*ld + kc*Kc + k, where batch=slice%nb, kc=slice/nb.
template<int TM, int TN, int MODE, bool OUT_F32>
__global__ __launch_bounds__(256)
void gemm_nt(const __hip_bfloat16* __restrict__ Ap, const __hip_bfloat16* __restrict__ Bp,
             void* __restrict__ Cp, int N, int Kc, int ldA, int ldB,
             long sA, long sB, long sC, int nb, float scale)
{
    constexpr int FM = TM / 32;   // 16x16 fragment rows per wave
    constexpr int FN = TN / 32;

    __shared__ __hip_bfloat16 At[2][TM][32];   // double-buffered, linear (gload_lds)
    __shared__ __hip_bfloat16 Bt[2][TN][32];

    const int gx = (int)gridDim.x, gy = (int)gridDim.y, gz = (int)gridDim.z;
    int slice, tile;
    if (MODE == 0) {
        slice = blockIdx.z;
        int wg = blockIdx.y * gx + blockIdx.x;
        const int cpx = (gx * gy) >> 3;
        tile = (wg & 7) * cpx + (wg >> 3);
    } else {
        const int h = ((int)blockIdx.z * gy + (int)blockIdx.y) * gx + (int)blockIdx.x;
        const int xcd = h & 7, k = h >> 3;
        if (MODE == 1) {
            const int SL = gz >> 3;              // slices per XCD
            slice = xcd + 8 * (k % SL);
            tile  = k / SL;
        } else {                                  // MODE 2
            slice = xcd % gz;                     // batch
            tile  = (xcd / gz) * ((gx * gy * gz) >> 3) + k;
        }
    }
    const int batch = slice % nb;
    const int kc    = slice / nb;
    const int n0 = (tile % gx) * TN;
    const int m0 = (tile / gx) * TM;

    const int tid  = threadIdx.x;
    const int lane = tid & 63;
    const int wave = tid >> 6;
    const int wm = (wave & 1) * (TM / 2);
    const int wn = (wave >> 1) * (TN / 2);
    const int l16 = lane & 15;
    const int lq  = lane >> 4;        // 0..3

    // staging: per wave, instr i fills a contiguous 1KB LDS stripe.
    const int aoff = wave * (TM * 8) + lane * 8;
    const int boff = wave * (TN * 8) + lane * 8;
    const int arow = aoff >> 5, acol = aoff & 31;
    const int brow = boff >> 5, bcol = boff & 31;

    const __hip_bfloat16* Ab = Ap + (size_t)batch * sA + (size_t)kc * Kc;
    const __hip_bfloat16* Bb = Bp + (size_t)batch * sB + (size_t)kc * Kc;

    auto stage = [&](int buf, int k0) {
        #pragma unroll
        for (int i = 0; i < TM / 64; ++i)
            gload16(Ab + (size_t)(m0 + arow + i * 16) * ldA + k0 + acol,
                    &At[buf][0][0] + aoff + i * 512);
        #pragma unroll
        for (int i = 0; i < TN / 64; ++i)
            gload16(Bb + (size_t)(n0 + brow + i * 16) * ldB + k0 + bcol,
                    &Bt[buf][0][0] + boff + i * 512);
    };

    f32x4 acc[FM][FN];
    #pragma unroll
    for (int i = 0; i < FM; ++i)
        #pragma unroll
        for (int j = 0; j < FN; ++j)
            acc[i][j] = (f32x4){0.f, 0.f, 0.f, 0.f};

    stage(0, 0);
    __syncthreads();                       // drain prologue stage

    const int nt = Kc >> 5;
    for (int t = 0; t < nt; ++t) {
        const int cur = t & 1;
        if (t + 1 < nt) stage(cur ^ 1, (t + 1) << 5);   // prefetch next tile

        // fragments: A[m=lane&15][k=(lane>>4)*8+j], B mirrored (harness-verified)
        bf16x8 av[FM], bv[FN];
        #pragma unroll
        for (int i = 0; i < FM; ++i)
            av[i] = *(const bf16x8*)&At[cur][wm + i * 16 + l16][lq * 8];
        #pragma unroll
        for (int j = 0; j < FN; ++j)
            bv[j] = *(const bf16x8*)&Bt[cur][wn + j * 16 + l16][lq * 8];
        #pragma unroll
        for (int i = 0; i < FM; ++i)
            #pragma unroll
            for (int j = 0; j < FN; ++j)
                acc[i][j] = __builtin_amdgcn_mfma_f32_16x16x32_bf16(av[i], bv[j], acc[i][j], 0, 0, 0);
        __syncthreads();   // single barrier/K-step: drains prefetch vmcnt + lgkm
    }

    // epilogue: C/D layout col=lane&15, row=(lane>>4)*4+reg (m89/m91-verified)
    float* Cf = (float*)Cp;
    __hip_bfloat16* Ch = (__hip_bfloat16*)Cp;
    const size_t cb0 = (size_t)slice * sC;
    #pragma unroll
    for (int i = 0; i < FM; ++i) {
        #pragma unroll
        for (int j = 0; j < FN; ++j) {
            const int row0 = m0 + wm + i * 16 + lq * 4;
            const int col  = n0 + wn + j * 16 + l16;
            #pragma unroll
            for (int r = 0; r < 4; ++r) {
                float v = acc[i][j][r] * scale;
                size_t idx = cb0 + (size_t)(row0 + r) * N + col;
                if (OUT_F32) Cf[idx] = v;
                else         Ch[idx] = __float2bfloat16(v);
            }
        }
    }
}

// Gb[b] = bf16( Gpart[b] + Gpart[4+b] ), bf16 partials, 8 elems/thread.
__global__ __launch_bounds__(256)
void reduce_kchunks(const unsigned short* __restrict__ part,
                    unsigned short* __restrict__ out)
{
    const size_t l = ((size_t)blockIdx.x * 256 + threadIdx.x) * 8;
    const size_t DD4 = (size_t)4 << 20;   // 4 * D * D elements
    union { unsigned short h[8]; uint4 u; } a, b, o;
    a.u = *(const uint4*)(part + l);
    b.u = *(const uint4*)(part + l + DD4);
    #pragma unroll
    for (int j = 0; j < 8; ++j) {
        union { float f; unsigned int u; } fa, fb;
        fa.u = (unsigned int)a.h[j] << 16;
        fb.u = (unsigned int)b.h[j] << 16;
        o.h[j] = bf16bits(fa.f + fb.f);
    }
    *(uint4*)(out + l) = o.u;
}

// Tiled transpose + fp32->bf16 cast: in (R x C) fp32 row-major -> out (C x R) bf16.
// Batches b < nsb additionally emit a straight row-major bf16 copy (fused cast).
#define TP 64
__global__ __launch_bounds__(256)
void transpose_cast(const float* __restrict__ in, __hip_bfloat16* __restrict__ out,
                    __hip_bfloat16* __restrict__ straight, int nsb,
                    int R, int C, long inStride, long outStride)
{
    __shared__ __hip_bfloat16 t2[TP][TP + 4];   // pitch 68: 8B-aligned row reads
    const int b  = blockIdx.z;
    const int r0 = blockIdx.x * TP;
    const int c0 = blockIdx.y * TP;
    const float* inb = in + (size_t)b * inStride;
    __hip_bfloat16* outb = out + (size_t)b * outStride;
    __hip_bfloat16* stb  = straight + (size_t)b * inStride;   // same shape as input
    const int t  = threadIdx.x;       // 0..255
    const int rr = t >> 4;            // 0..15
    const int c4 = (t & 15) * 4;
    #pragma unroll
    for (int p = 0; p < 4; ++p) {
        const int row = p * 16 + rr;
        float4 f = *(const float4*)&inb[(size_t)(r0 + row) * C + c0 + c4];
        union { __hip_bfloat16 h[4]; uint2 u; } s;
        s.h[0] = __float2bfloat16(f.x); s.h[1] = __float2bfloat16(f.y);
        s.h[2] = __float2bfloat16(f.z); s.h[3] = __float2bfloat16(f.w);
        t2[c4 + 0][row] = s.h[0];
        t2[c4 + 1][row] = s.h[1];
        t2[c4 + 2][row] = s.h[2];
        t2[c4 + 3][row] = s.h[3];
        if (b < nsb)
            *(uint2*)&stb[(size_t)(r0 + row) * C + c0 + c4] = s.u;
    }
    __syncthreads();
    #pragma unroll
    for (int p = 0; p < 4; ++p) {
        const int crow = p * 16 + rr;     // output row = input column c0+crow
        union { __hip_bfloat16 h[4]; uint2 u; } o;
        #pragma unroll
        for (int j = 0; j < 4; ++j) o.h[j] = t2[crow][c4 + j];
        *(uint2*)&outb[(size_t)(c0 + crow) * R + r0 + c4] = o.u;
    }
}

__global__ __launch_bounds__(256)
void cast_f32_bf16(const float* __restrict__ in, __hip_bfloat16* __restrict__ out, int n)
{
    const int i = (blockIdx.x * 256 + threadIdx.x) << 2;
    if (i >= n) return;
    float4 f = *(const float4*)(in + i);
    union { __hip_bfloat16 h[4]; uint2 u; } t;
    t.h[0] = __float2bfloat16(f.x); t.h[1] = __float2bfloat16(f.y);
    t.h[2] = __float2bfloat16(f.z); t.h[3] = __float2bfloat16(f.w);
    *(uint2*)(out + i) = t.u;
}

extern "C" void kernel_launch(void* const* d_in, const int* in_sizes, int n_in,
                              void* d_out, int out_size, void* d_ws, size_t ws_size,
                              hipStream_t stream)
{
    const int Bz = 4, T = 4096, D = 1024;
    const float gamma = 32.0f;  // sqrt(1024)

    const float* x  = (const float*)d_in[0];
    const float* wq = (const float*)d_in[1];
    const float* wk = (const float*)d_in[2];
    const float* wv = (const float*)d_in[3];
    float* y = (float*)d_out;

    // workspace layout (32 MB total)
    unsigned char* p = (unsigned char*)d_ws;
    const size_t DD = (size_t)D * D;
    __hip_bfloat16* Gb  = (__hip_bfloat16*)p; p += Bz * DD * 2;   //  8 MB
    __hip_bfloat16* Hb  = (__hip_bfloat16*)p; p += Bz * DD * 2;   //  8 MB
    __hip_bfloat16* PTb = (__hip_bfloat16*)p; p += Bz * DD * 2;   //  8 MB
    __hip_bfloat16* wqb = (__hip_bfloat16*)p; p += DD * 2;        //  2 MB
    __hip_bfloat16* wkb = (__hip_bfloat16*)p; p += DD * 2;        //  2 MB
    __hip_bfloat16* wvT = (__hip_bfloat16*)p; p += DD * 2;        //  2 MB
    __hip_bfloat16* C0b = (__hip_bfloat16*)p; p += DD * 2;        //  2 MB
    __hip_bfloat16* Gpart = Hb;                                   // 16 MB (Hb+PTb), dead after reduce
    __hip_bfloat16* xb23  = Gb;                                   // 16 MB (Gb+Hb), written after P GEMM

    __hip_bfloat16* xbT  = (__hip_bfloat16*)d_out;                                  // [0,32M)
    __hip_bfloat16* xb01 = (__hip_bfloat16*)((unsigned char*)d_out + ((size_t)32 << 20)); // [32,48M)

    dim3 blk(256);

    // weight casts / transposes; x transpose fuses the bf16 row-major copy of b0,b1
    cast_f32_bf16<<<dim3((int)(DD / 1024)), blk, 0, stream>>>(wq, wqb, (int)DD);
    cast_f32_bf16<<<dim3((int)(DD / 1024)), blk, 0, stream>>>(wk, wkb, (int)DD);
    transpose_cast<<<dim3(D / TP, D / TP, 1), blk, 0, stream>>>(
        wv, wvT, wvT, 0, D, D, 0, 0);
    transpose_cast<<<dim3(T / TP, D / TP, Bz), blk, 0, stream>>>(
        x, xbT, xb01, 2, T, D, (long)T * D, (long)D * T);

    // C0 = w_q w_k^T                      : NT(wq, wk)       64x128, MODE 0
    gemm_nt<64, 128, 0, false><<<dim3(D / 128, D / 64, 1), blk, 0, stream>>>(
        wqb, wkb, C0b, D, D, D, D, 0, 0, 0, 1, 1.0f);
    // Gpart[kc*4+b] = xbT[b][:, kc*2048:+2048] x same : split-K=2, slice->XCD pin
    gemm_nt<128, 128, 1, false><<<dim3(D / 128, D / 128, 2 * Bz), blk, 0, stream>>>(
        xbT, xbT, Gpart, D, T / 2, T, T, (long)D * T, (long)D * T, (long)DD, Bz, 1.0f);
    // Gb = bf16(Gpart[b] + Gpart[4+b])
    reduce_kchunks<<<dim3((int)(Bz * DD / 2048)), blk, 0, stream>>>(
        (const unsigned short*)Gpart, (unsigned short*)Gb);
    // H_b = C0 G_b (G symmetric)          : NT(C0, G)        64x128, batch->XCD pin
    gemm_nt<64, 128, 2, false><<<dim3(D / 128, D / 64, Bz), blk, 0, stream>>>(
        C0b, Gb, Hb, D, D, D, D, 0, (long)DD, (long)DD, Bz, 1.0f);
    // P_b^T = gamma * w_v^T H_b^T         : NT(wvT, H)       64x128, batch->XCD pin
    gemm_nt<64, 128, 2, false><<<dim3(D / 128, D / 64, Bz), blk, 0, stream>>>(
        wvT, Hb, PTb, D, D, D, D, 0, (long)DD, (long)DD, Bz, gamma);

    // xb23 = bf16(x[b2,b3]) into dead Gb+Hb slots (stream-ordered after P GEMM)
    cast_f32_bf16<<<dim3((int)(2 * (size_t)T * D / 1024)), blk, 0, stream>>>(
        x + (size_t)2 * T * D, xb23, (int)(2 * (size_t)T * D));

    // y_b = x_b P_b : NT(xb, P^T), fp32 out, two dispatches for buffer liveness
    // A: batches 0,1 read xb01 @ d_out[32,48M), write y @ d_out[0,32M)
    gemm_nt<128, 128, 2, true><<<dim3(D / 128, T / 128, 2), blk, 0, stream>>>(
        xb01, PTb, y, D, D, D, D, (long)T * D, (long)DD, (long)T * D, 2, 1.0f);
    // B: batches 2,3 read xb23 @ ws, write y @ d_out[32,64M) (xb01 dead)
    gemm_nt<128, 128, 2, true><<<dim3(D / 128, T / 128, 2), blk, 0, stream>>>(
        xb23, PTb + 2 * DD, y + (size_t)2 * T * D, D, D, D, D,
        (long)T * D, (long)DD, (long)T * D, 2, 1.0f);
}

// Round 5
// 293.639 us; speedup vs baseline: 1.2534x; 1.0124x over previous
//
#include <hip/hip_runtime.h>
#include <hip/hip_bf16.h>

// y = x @ P,  P = gamma * (w_q w_k^T) (x^T x) w_v      (no softmax => associativity)
// All GEMMs: NT form  C[m][n] = scale * sum_k A[m][k] * B[n][k], all operands bf16,
// global_load_lds width-16 staging, double-buffered LDS (1 barrier / K-step),
// XCD-pinned block scheduling (MODE 1: slice->XCD, MODE 2: batch->XCD),
// T2 LDS slot-XOR swizzle (conflict-free fragment reads; swizzle applied on the
// GLOBAL source address since global_load_lds writes linearly, rule #21).
//
// Buffer choreography (stream-ordered dispatches):
//   d_out[ 0,32M): xbT   (bf16 x^T, per batch D x T)     dead after G GEMM
//   d_out[32,48M): xb01  (bf16 x rows, batches 0,1)      dead after y-dispatch-A
//   ws: Gb | Hb | PTb | wqb wkb wvT C0b
//   G split-K partials (bf16, 16M) live in Hb+PTb slots  dead after reduce
//   xb23 (bf16 x rows, batches 2,3) lives in Gb+Hb slots (cast after P GEMM)
//   y-dispatch-A writes d_out[0,32M); y-dispatch-B writes d_out[32,64M).

typedef __attribute__((ext_vector_type(8))) short bf16x8;   // 8 x bf16 (4 VGPRs)
typedef __attribute__((ext_vector_type(4))) float f32x4;    // 4 x fp32 accum

__device__ __forceinline__ unsigned short bf16bits(float f) {
    union { __hip_bfloat16 b; unsigned short s; } r;
    r.b = __float2bfloat16(f);
    return r.s;
}

// async global->LDS, 16B per lane; LDS dest must be wave-uniform base + lane*16.
__device__ __forceinline__ void gload16(const void* g, void* l) {
    __builtin_amdgcn_global_load_lds((__attribute__((address_space(1))) void*)g,
                                     (__attribute__((address_space(3))) void*)l,
                                     16, 0, 0);
}

// TM x TN block tile, BK=32, 256 threads (4 waves 2x2), per-wave (TM/2)x(TN/2).
// Block scheduling by MODE (h = hardware linear block id, XCD ~ h%8):
//   MODE 0: slice = blockIdx.z; chunked (x,y) swizzle (8-XCD m-row chunks).
//   MODE 1: slice-pinned. gz % 8 == 0. Each XCD owns gz/8 whole slices ->
//           slice's operand panels stay resident in that XCD's L2.
//   MODE 2: batch-pinned. gz = nb (<=8, divides 8). XCD serves one batch;
//           8/nb XCDs per batch, each owning a contiguous m-row tile chunk.
// Operand offset: batch*s + row*ld + kc*Kc + k, where batch=slice%nb, kc=slice/nb.
//
// T2 swizzle: 64B LDS row = 4 x 16B slots; phys_slot = log_slot ^ ((row>>1)&3).
// Fragment read bank-quad = 4*(row&1) + (lq ^ ((l16>>1)&3)) -> 16 lanes cover all
// 8 quads exactly 2x (2-way = free, m136). Staging keeps LDS linear and permutes
// the per-lane global column instead (same 64B segments -> coalescing unchanged).
template<int TM, int TN, int MODE, bool OUT_F32>
__global__ __launch_bounds__(256)
void gemm_nt(const __hip_bfloat16* __restrict__ Ap, const __hip_bfloat16* __restrict__ Bp,
             void* __restrict__ Cp, int N, int Kc, int ldA, int ldB,
             long sA, long sB, long sC, int nb, float scale)
{
    constexpr int FM = TM / 32;   // 16x16 fragment rows per wave
    constexpr int FN = TN / 32;

    __shared__ __hip_bfloat16 At[2][TM][32];   // double-buffered, linear (gload_lds)
    __shared__ __hip_bfloat16 Bt[2][TN][32];

    const int gx = (int)gridDim.x, gy = (int)gridDim.y, gz = (int)gridDim.z;
    int slice, tile;
    if (MODE == 0) {
        slice = blockIdx.z;
        int wg = blockIdx.y * gx + blockIdx.x;
        const int cpx = (gx * gy) >> 3;
        tile = (wg & 7) * cpx + (wg >> 3);
    } else {
        const int h = ((int)blockIdx.z * gy + (int)blockIdx.y) * gx + (int)blockIdx.x;
        const int xcd = h & 7, k = h >> 3;
        if (MODE == 1) {
            const int SL = gz >> 3;              // slices per XCD
            slice = xcd + 8 * (k % SL);
            tile  = k / SL;
        } else {                                  // MODE 2
            slice = xcd % gz;                     // batch
            tile  = (xcd / gz) * ((gx * gy * gz) >> 3) + k;
        }
    }
    const int batch = slice % nb;
    const int kc    = slice / nb;
    const int n0 = (tile % gx) * TN;
    const int m0 = (tile / gx) * TM;

    const int tid  = threadIdx.x;
    const int lane = tid & 63;
    const int wave = tid >> 6;
    const int wm = (wave & 1) * (TM / 2);
    const int wn = (wave >> 1) * (TN / 2);
    const int l16 = lane & 15;
    const int lq  = lane >> 4;        // 0..3

    // staging: per wave, instr i fills a contiguous 1KB LDS stripe.
    const int aoff = wave * (TM * 8) + lane * 8;
    const int boff = wave * (TN * 8) + lane * 8;
    const int arow = aoff >> 5, brow = boff >> 5;
    // swizzled source column base: slot s=(off>>3)&3, row r=off>>5 -> (s^((r>>1)&3))*8
    // (invariant across the i*512 stripe steps: +16 rows / +64 slots keep both terms)
    const int acs = (((aoff >> 3) & 3) ^ ((aoff >> 6) & 3)) << 3;
    const int bcs = (((boff >> 3) & 3) ^ ((boff >> 6) & 3)) << 3;
    // swizzled fragment-read column (elems), constant per lane across i/j:
    const int sc = (lq ^ ((l16 >> 1) & 3)) << 3;

    const __hip_bfloat16* Ab = Ap + (size_t)batch * sA + (size_t)kc * Kc;
    const __hip_bfloat16* Bb = Bp + (size_t)batch * sB + (size_t)kc * Kc;

    auto stage = [&](int buf, int k0) {
        #pragma unroll
        for (int i = 0; i < TM / 64; ++i)
            gload16(Ab + (size_t)(m0 + arow + i * 16) * ldA + k0 + acs,
                    &At[buf][0][0] + aoff + i * 512);
        #pragma unroll
        for (int i = 0; i < TN / 64; ++i)
            gload16(Bb + (size_t)(n0 + brow + i * 16) * ldB + k0 + bcs,
                    &Bt[buf][0][0] + boff + i * 512);
    };

    f32x4 acc[FM][FN];
    #pragma unroll
    for (int i = 0; i < FM; ++i)
        #pragma unroll
        for (int j = 0; j < FN; ++j)
            acc[i][j] = (f32x4){0.f, 0.f, 0.f, 0.f};

    stage(0, 0);
    __syncthreads();                       // drain prologue stage

    const int nt = Kc >> 5;
    for (int t = 0; t < nt; ++t) {
        const int cur = t & 1;
        if (t + 1 < nt) stage(cur ^ 1, (t + 1) << 5);   // prefetch next tile

        // fragments: logical A[m=lane&15][k=lq*8+j]; physical col = sc (swizzled)
        bf16x8 av[FM], bv[FN];
        #pragma unroll
        for (int i = 0; i < FM; ++i)
            av[i] = *(const bf16x8*)&At[cur][wm + i * 16 + l16][sc];
        #pragma unroll
        for (int j = 0; j < FN; ++j)
            bv[j] = *(const bf16x8*)&Bt[cur][wn + j * 16 + l16][sc];
        #pragma unroll
        for (int i = 0; i < FM; ++i)
            #pragma unroll
            for (int j = 0; j < FN; ++j)
                acc[i][j] = __builtin_amdgcn_mfma_f32_16x16x32_bf16(av[i], bv[j], acc[i][j], 0, 0, 0);
        __syncthreads();   // single barrier/K-step: drains prefetch vmcnt + lgkm
    }

    // epilogue: C/D layout col=lane&15, row=(lane>>4)*4+reg (m89/m91-verified)
    float* Cf = (float*)Cp;
    __hip_bfloat16* Ch = (__hip_bfloat16*)Cp;
    const size_t cb0 = (size_t)slice * sC;
    #pragma unroll
    for (int i = 0; i < FM; ++i) {
        #pragma unroll
        for (int j = 0; j < FN; ++j) {
            const int row0 = m0 + wm + i * 16 + lq * 4;
            const int col  = n0 + wn + j * 16 + l16;
            #pragma unroll
            for (int r = 0; r < 4; ++r) {
                float v = acc[i][j][r] * scale;
                size_t idx = cb0 + (size_t)(row0 + r) * N + col;
                if (OUT_F32) Cf[idx] = v;
                else         Ch[idx] = __float2bfloat16(v);
            }
        }
    }
}

// Gb[b] = bf16( Gpart[b] + Gpart[4+b] ), bf16 partials, 8 elems/thread.
__global__ __launch_bounds__(256)
void reduce_kchunks(const unsigned short* __restrict__ part,
                    unsigned short* __restrict__ out)
{
    const size_t l = ((size_t)blockIdx.x * 256 + threadIdx.x) * 8;
    const size_t DD4 = (size_t)4 << 20;   // 4 * D * D elements
    union { unsigned short h[8]; uint4 u; } a, b, o;
    a.u = *(const uint4*)(part + l);
    b.u = *(const uint4*)(part + l + DD4);
    #pragma unroll
    for (int j = 0; j < 8; ++j) {
        union { float f; unsigned int u; } fa, fb;
        fa.u = (unsigned int)a.h[j] << 16;
        fb.u = (unsigned int)b.h[j] << 16;
        o.h[j] = bf16bits(fa.f + fb.f);
    }
    *(uint4*)(out + l) = o.u;
}

// Tiled transpose + fp32->bf16 cast: in (R x C) fp32 row-major -> out (C x R) bf16.
// Batches b < nsb additionally emit a straight row-major bf16 copy (fused cast).
#define TP 64
__global__ __launch_bounds__(256)
void transpose_cast(const float* __restrict__ in, __hip_bfloat16* __restrict__ out,
                    __hip_bfloat16* __restrict__ straight, int nsb,
                    int R, int C, long inStride, long outStride)
{
    __shared__ __hip_bfloat16 t2[TP][TP + 4];   // pitch 68: 8B-aligned row reads
    const int b  = blockIdx.z;
    const int r0 = blockIdx.x * TP;
    const int c0 = blockIdx.y * TP;
    const float* inb = in + (size_t)b * inStride;
    __hip_bfloat16* outb = out + (size_t)b * outStride;
    __hip_bfloat16* stb  = straight + (size_t)b * inStride;   // same shape as input
    const int t  = threadIdx.x;       // 0..255
    const int rr = t >> 4;            // 0..15
    const int c4 = (t & 15) * 4;
    #pragma unroll
    for (int p = 0; p < 4; ++p) {
        const int row = p * 16 + rr;
        float4 f = *(const float4*)&inb[(size_t)(r0 + row) * C + c0 + c4];
        union { __hip_bfloat16 h[4]; uint2 u; } s;
        s.h[0] = __float2bfloat16(f.x); s.h[1] = __float2bfloat16(f.y);
        s.h[2] = __float2bfloat16(f.z); s.h[3] = __float2bfloat16(f.w);
        t2[c4 + 0][row] = s.h[0];
        t2[c4 + 1][row] = s.h[1];
        t2[c4 + 2][row] = s.h[2];
        t2[c4 + 3][row] = s.h[3];
        if (b < nsb)
            *(uint2*)&stb[(size_t)(r0 + row) * C + c0 + c4] = s.u;
    }
    __syncthreads();
    #pragma unroll
    for (int p = 0; p < 4; ++p) {
        const int crow = p * 16 + rr;     // output row = input column c0+crow
        union { __hip_bfloat16 h[4]; uint2 u; } o;
        #pragma unroll
        for (int j = 0; j < 4; ++j) o.h[j] = t2[crow][c4 + j];
        *(uint2*)&outb[(size_t)(c0 + crow) * R + r0 + c4] = o.u;
    }
}

__global__ __launch_bounds__(256)
void cast_f32_bf16(const float* __restrict__ in, __hip_bfloat16* __restrict__ out, int n)
{
    const int i = (blockIdx.x * 256 + threadIdx.x) << 2;
    if (i >= n) return;
    float4 f = *(const float4*)(in + i);
    union { __hip_bfloat16 h[4]; uint2 u; } t;
    t.h[0] = __float2bfloat16(f.x); t.h[1] = __float2bfloat16(f.y);
    t.h[2] = __float2bfloat16(f.z); t.h[3] = __float2bfloat16(f.w);
    *(uint2*)(out + i) = t.u;
}

extern "C" void kernel_launch(void* const* d_in, const int* in_sizes, int n_in,
                              void* d_out, int out_size, void* d_ws, size_t ws_size,
                              hipStream_t stream)
{
    const int Bz = 4, T = 4096, D = 1024;
    const float gamma = 32.0f;  // sqrt(1024)

    const float* x  = (const float*)d_in[0];
    const float* wq = (const float*)d_in[1];
    const float* wk = (const float*)d_in[2];
    const float* wv = (const float*)d_in[3];
    float* y = (float*)d_out;

    // workspace layout (32 MB total)
    unsigned char* p = (unsigned char*)d_ws;
    const size_t DD = (size_t)D * D;
    __hip_bfloat16* Gb  = (__hip_bfloat16*)p; p += Bz * DD * 2;   //  8 MB
    __hip_bfloat16* Hb  = (__hip_bfloat16*)p; p += Bz * DD * 2;   //  8 MB
    __hip_bfloat16* PTb = (__hip_bfloat16*)p; p += Bz * DD * 2;   //  8 MB
    __hip_bfloat16* wqb = (__hip_bfloat16*)p; p += DD * 2;        //  2 MB
    __hip_bfloat16* wkb = (__hip_bfloat16*)p; p += DD * 2;        //  2 MB
    __hip_bfloat16* wvT = (__hip_bfloat16*)p; p += DD * 2;        //  2 MB
    __hip_bfloat16* C0b = (__hip_bfloat16*)p; p += DD * 2;        //  2 MB
    __hip_bfloat16* Gpart = Hb;                                   // 16 MB (Hb+PTb), dead after reduce
    __hip_bfloat16* xb23  = Gb;                                   // 16 MB (Gb+Hb), written after P GEMM

    __hip_bfloat16* xbT  = (__hip_bfloat16*)d_out;                                  // [0,32M)
    __hip_bfloat16* xb01 = (__hip_bfloat16*)((unsigned char*)d_out + ((size_t)32 << 20)); // [32,48M)

    dim3 blk(256);

    // weight casts / transposes; x transpose fuses the bf16 row-major copy of b0,b1
    cast_f32_bf16<<<dim3((int)(DD / 1024)), blk, 0, stream>>>(wq, wqb, (int)DD);
    cast_f32_bf16<<<dim3((int)(DD / 1024)), blk, 0, stream>>>(wk, wkb, (int)DD);
    transpose_cast<<<dim3(D / TP, D / TP, 1), blk, 0, stream>>>(
        wv, wvT, wvT, 0, D, D, 0, 0);
    transpose_cast<<<dim3(T / TP, D / TP, Bz), blk, 0, stream>>>(
        x, xbT, xb01, 2, T, D, (long)T * D, (long)D * T);

    // C0 = w_q w_k^T                      : NT(wq, wk)       64x128, MODE 0
    gemm_nt<64, 128, 0, false><<<dim3(D / 128, D / 64, 1), blk, 0, stream>>>(
        wqb, wkb, C0b, D, D, D, D, 0, 0, 0, 1, 1.0f);
    // Gpart[kc*4+b] = xbT[b][:, kc*2048:+2048] x same : split-K=2, slice->XCD pin
    gemm_nt<128, 128, 1, false><<<dim3(D / 128, D / 128, 2 * Bz), blk, 0, stream>>>(
        xbT, xbT, Gpart, D, T / 2, T, T, (long)D * T, (long)D * T, (long)DD, Bz, 1.0f);
    // Gb = bf16(Gpart[b] + Gpart[4+b])
    reduce_kchunks<<<dim3((int)(Bz * DD / 2048)), blk, 0, stream>>>(
        (const unsigned short*)Gpart, (unsigned short*)Gb);
    // H_b = C0 G_b (G symmetric)          : NT(C0, G)        64x128, batch->XCD pin
    gemm_nt<64, 128, 2, false><<<dim3(D / 128, D / 64, Bz), blk, 0, stream>>>(
        C0b, Gb, Hb, D, D, D, D, 0, (long)DD, (long)DD, Bz, 1.0f);
    // P_b^T = gamma * w_v^T H_b^T         : NT(wvT, H)       64x128, batch->XCD pin
    gemm_nt<64, 128, 2, false><<<dim3(D / 128, D / 64, Bz), blk, 0, stream>>>(
        wvT, Hb, PTb, D, D, D, D, 0, (long)DD, (long)DD, Bz, gamma);

    // xb23 = bf16(x[b2,b3]) into dead Gb+Hb slots (stream-ordered after P GEMM)
    cast_f32_bf16<<<dim3((int)(2 * (size_t)T * D / 1024)), blk, 0, stream>>>(
        x + (size_t)2 * T * D, xb23, (int)(2 * (size_t)T * D));

    // y_b = x_b P_b : NT(xb, P^T), fp32 out, two dispatches for buffer liveness
    // A: batches 0,1 read xb01 @ d_out[32,48M), write y @ d_out[0,32M)
    gemm_nt<128, 128, 2, true><<<dim3(D / 128, T / 128, 2), blk, 0, stream>>>(
        xb01, PTb, y, D, D, D, D, (long)T * D, (long)DD, (long)T * D, 2, 1.0f);
    // B: batches 2,3 read xb23 @ ws, write y @ d_out[32,64M) (xb01 dead)
    gemm_nt<128, 128, 2, true><<<dim3(D / 128, T / 128, 2), blk, 0, stream>>>(
        xb23, PTb + 2 * DD, y + (size_t)2 * T * D, D, D, D, D,
        (long)T * D, (long)DD, (long)T * D, 2, 1.0f);
}

// Round 6
// 275.571 us; speedup vs baseline: 1.3356x; 1.0656x over previous
//
#include <hip/hip_runtime.h>
#include <hip/hip_bf16.h>

// y = x @ P,  P = gamma * (w_q w_k^T) (x^T x) w_v      (no softmax => associativity)
// All GEMMs: NT form  C[m][n] = scale * sum_k A[m][k] * B[n][k], all operands bf16.
// Big GEMMs (G, y): gemm8 — 256x128 tile, 8 waves, BK=64, TRIPLE-buffered LDS,
//   counted s_waitcnt vmcnt(6) (T4: loads in flight across barriers), one raw
//   s_barrier per K-tile (T3), setprio around MFMA cluster (T5), T2 slot-XOR
//   swizzle (global-source side, linear gload_lds dest), XCD-pinned grids (T1).
// Small GEMMs (C0, H, P): proven 2-phase 64x128 kernel.
//
// Buffer choreography (stream-ordered dispatches):
//   d_out[ 0,32M): xbT   (bf16 x^T, per batch D x T)     dead after G GEMM
//   d_out[32,48M): xb01  (bf16 x rows, batches 0,1)      dead after y-dispatch-A
//   ws: Gb | Hb | PTb | wqb wkb wvT C0b
//   G split-K partials (bf16, 16M) live in Hb+PTb slots  dead after reduce
//   xb23 (bf16 x rows, batches 2,3) lives in Gb+Hb slots (cast after P GEMM)
//   y-dispatch-A writes d_out[0,32M); y-dispatch-B writes d_out[32,64M).

typedef __attribute__((ext_vector_type(8))) short bf16x8;   // 8 x bf16 (4 VGPRs)
typedef __attribute__((ext_vector_type(4))) float f32x4;    // 4 x fp32 accum

__device__ __forceinline__ unsigned short bf16bits(float f) {
    union { __hip_bfloat16 b; unsigned short s; } r;
    r.b = __float2bfloat16(f);
    return r.s;
}

// async global->LDS, 16B per lane; LDS dest must be wave-uniform base + lane*16.
__device__ __forceinline__ void gload16(const void* g, void* l) {
    __builtin_amdgcn_global_load_lds((__attribute__((address_space(1))) void*)g,
                                     (__attribute__((address_space(3))) void*)l,
                                     16, 0, 0);
}

// ---------------------------------------------------------------------------
// gemm8: BM=256 x BN=128, BK=64, 512 threads (8 waves, 4m x 2n), per-wave 64x64.
// Pipeline: 3 LDS buffers, depth-2 prefetch. Per K-tile:
//   s_waitcnt vmcnt(6)  (tile t's 6 loads/wave done; t+1,t+2 still in flight)
//   s_barrier           (all waves' tile-t loads in LDS; prev-iter reads done)
//   stage tile t+2 into buf[(t+2)%3]   (safe: last read at iter t-1, barrier'd)
//   ds_read 16 frags (swizzled) ; 32 MFMA under setprio
// No vmcnt(0) drain in the loop. Proof of no race: a wave arrives at barrier(t)
// only after its iter t-1 MFMAs, whose lgkm waits imply its buf[(t-1)%3]
// ds_reads completed; buf[(t+2)%3] == buf[(t-1)%3].
// Swizzle: phys 16B slot = logical slot ^ (row&7); applied by permuting the
// per-lane GLOBAL source column (dest linear, rule #21); reads use same XOR.
// MODE 1: slice = h&7 (slice->XCD pin).  MODE 2: batch = (h&7)%nb, contiguous
// m-chunks per XCD.  Grid must be 256 blocks (1 block/CU, 8 waves).
// ---------------------------------------------------------------------------
template<int MODE, bool OUT_F32>
__global__ __launch_bounds__(512, 2)
void gemm8(const __hip_bfloat16* __restrict__ Ap, const __hip_bfloat16* __restrict__ Bp,
           void* __restrict__ Cp, int N, int Kc, int ldA, int ldB,
           long sA, long sB, long sC, int nb, int tnc, float scale)
{
    constexpr int BM = 256, BN = 128, BK = 64;
    __shared__ __hip_bfloat16 lds[3][(BM + BN) * BK];   // 3 x 48KB = 144 KB

    const int h = blockIdx.x;
    int slice, tile;
    if (MODE == 1) { slice = h & 7; tile = h >> 3; }
    else {
        const int xcd = h & 7;
        slice = xcd % nb;
        tile  = (xcd / nb) * ((int)gridDim.x >> 3) + (h >> 3);
    }
    const int batch = slice % nb, kc = slice / nb;
    const int n0 = (tile % tnc) * BN;
    const int m0 = (tile / tnc) * BM;

    const int tid  = threadIdx.x;
    const int lane = tid & 63;
    const int w    = tid >> 6;
    const int wm = (w >> 1) * 64, wn = (w & 1) * 64;
    const int l16 = lane & 15, lq = lane >> 4;

    // staging: wave-instr i covers 8 rows x 128B; per-lane source col swizzled
    const int srow = lane >> 3;                  // 0..7 within 8-row group
    const int scol = ((lane & 7) ^ srow) << 3;   // swizzled source col (elems)
    const int soff = w * 512 + lane * 8;         // LDS elem base (i=0)

    const __hip_bfloat16* Ab = Ap + (size_t)batch * sA + (size_t)kc * Kc;
    const __hip_bfloat16* Bb = Bp + (size_t)batch * sB + (size_t)kc * Kc;

    const int nt = Kc >> 6;
    auto stage = [&](int buf, int t) {
        const int k0 = (t < nt ? t : nt - 1) << 6;   // clamp: uniform 6 loads/iter
        __hip_bfloat16* L = &lds[buf][0];
        #pragma unroll
        for (int i = 0; i < 4; ++i)     // A: 256 rows
            gload16(Ab + (size_t)(m0 + i * 64 + w * 8 + srow) * ldA + k0 + scol,
                    L + i * 4096 + soff);
        #pragma unroll
        for (int i = 0; i < 2; ++i)     // B: 128 rows
            gload16(Bb + (size_t)(n0 + i * 64 + w * 8 + srow) * ldB + k0 + scol,
                    L + BM * BK + i * 4096 + soff);
    };

    f32x4 acc[4][4];
    #pragma unroll
    for (int i = 0; i < 4; ++i)
        #pragma unroll
        for (int j = 0; j < 4; ++j)
            acc[i][j] = (f32x4){0.f, 0.f, 0.f, 0.f};

    stage(0, 0);
    stage(1, 1);                                    // 12 loads/wave in flight

    for (int t = 0; t < nt; ++t) {
        asm volatile("s_waitcnt vmcnt(6)" ::: "memory");   // tile t landed
        __builtin_amdgcn_s_barrier();
        asm volatile("" ::: "memory");              // nothing hoists above barrier
        stage((t + 2) % 3, t + 2);                  // overlaps with compute below

        const __hip_bfloat16* LA = &lds[t % 3][0];
        const __hip_bfloat16* LB = LA + BM * BK;
        #pragma unroll
        for (int kk = 0; kk < 2; ++kk) {
            const int sc = ((kk * 4 + lq) ^ (l16 & 7)) << 3;   // swizzled read col
            bf16x8 av[4], bv[4];
            #pragma unroll
            for (int i = 0; i < 4; ++i)
                av[i] = *(const bf16x8*)&LA[(wm + i * 16 + l16) * BK + sc];
            #pragma unroll
            for (int j = 0; j < 4; ++j)
                bv[j] = *(const bf16x8*)&LB[(wn + j * 16 + l16) * BK + sc];
            __builtin_amdgcn_s_setprio(1);
            #pragma unroll
            for (int i = 0; i < 4; ++i)
                #pragma unroll
                for (int j = 0; j < 4; ++j)
                    acc[i][j] = __builtin_amdgcn_mfma_f32_16x16x32_bf16(av[i], bv[j], acc[i][j], 0, 0, 0);
            __builtin_amdgcn_s_setprio(0);
        }
    }
    asm volatile("s_waitcnt vmcnt(0)" ::: "memory");   // drain tail DMA before exit

    // epilogue: C/D layout col=lane&15, row=(lane>>4)*4+reg (m89/m91-verified)
    float* Cf = (float*)Cp;
    __hip_bfloat16* Ch = (__hip_bfloat16*)Cp;
    const size_t cb0 = (size_t)slice * sC;
    #pragma unroll
    for (int i = 0; i < 4; ++i) {
        #pragma unroll
        for (int j = 0; j < 4; ++j) {
            const int row0 = m0 + wm + i * 16 + lq * 4;
            const int col  = n0 + wn + j * 16 + l16;
            #pragma unroll
            for (int r = 0; r < 4; ++r) {
                float v = acc[i][j][r] * scale;
                size_t idx = cb0 + (size_t)(row0 + r) * N + col;
                if (OUT_F32) Cf[idx] = v;
                else         Ch[idx] = __float2bfloat16(v);
            }
        }
    }
}

// ---------------------------------------------------------------------------
// 2-phase 64x128 kernel (proven) for the small D^3 chain GEMMs (C0, H, P).
// ---------------------------------------------------------------------------
template<int TM, int TN, int MODE, bool OUT_F32>
__global__ __launch_bounds__(256)
void gemm_nt(const __hip_bfloat16* __restrict__ Ap, const __hip_bfloat16* __restrict__ Bp,
             void* __restrict__ Cp, int N, int Kc, int ldA, int ldB,
             long sA, long sB, long sC, int nb, float scale)
{
    constexpr int FM = TM / 32;
    constexpr int FN = TN / 32;

    __shared__ __hip_bfloat16 At[2][TM][32];
    __shared__ __hip_bfloat16 Bt[2][TN][32];

    const int gx = (int)gridDim.x, gy = (int)gridDim.y, gz = (int)gridDim.z;
    int slice, tile;
    if (MODE == 0) {
        slice = blockIdx.z;
        int wg = blockIdx.y * gx + blockIdx.x;
        const int cpx = (gx * gy) >> 3;
        tile = (wg & 7) * cpx + (wg >> 3);
    } else {
        const int h = ((int)blockIdx.z * gy + (int)blockIdx.y) * gx + (int)blockIdx.x;
        const int xcd = h & 7, k = h >> 3;
        if (MODE == 1) {
            const int SL = gz >> 3;
            slice = xcd + 8 * (k % SL);
            tile  = k / SL;
        } else {
            slice = xcd % gz;
            tile  = (xcd / gz) * ((gx * gy * gz) >> 3) + k;
        }
    }
    const int batch = slice % nb;
    const int kc    = slice / nb;
    const int n0 = (tile % gx) * TN;
    const int m0 = (tile / gx) * TM;

    const int tid  = threadIdx.x;
    const int lane = tid & 63;
    const int wave = tid >> 6;
    const int wm = (wave & 1) * (TM / 2);
    const int wn = (wave >> 1) * (TN / 2);
    const int l16 = lane & 15;
    const int lq  = lane >> 4;

    const int aoff = wave * (TM * 8) + lane * 8;
    const int boff = wave * (TN * 8) + lane * 8;
    const int arow = aoff >> 5, brow = boff >> 5;
    const int acs = (((aoff >> 3) & 3) ^ ((aoff >> 6) & 3)) << 3;
    const int bcs = (((boff >> 3) & 3) ^ ((boff >> 6) & 3)) << 3;
    const int sc = (lq ^ ((l16 >> 1) & 3)) << 3;

    const __hip_bfloat16* Ab = Ap + (size_t)batch * sA + (size_t)kc * Kc;
    const __hip_bfloat16* Bb = Bp + (size_t)batch * sB + (size_t)kc * Kc;

    auto stage = [&](int buf, int k0) {
        #pragma unroll
        for (int i = 0; i < TM / 64; ++i)
            gload16(Ab + (size_t)(m0 + arow + i * 16) * ldA + k0 + acs,
                    &At[buf][0][0] + aoff + i * 512);
        #pragma unroll
        for (int i = 0; i < TN / 64; ++i)
            gload16(Bb + (size_t)(n0 + brow + i * 16) * ldB + k0 + bcs,
                    &Bt[buf][0][0] + boff + i * 512);
    };

    f32x4 acc[FM][FN];
    #pragma unroll
    for (int i = 0; i < FM; ++i)
        #pragma unroll
        for (int j = 0; j < FN; ++j)
            acc[i][j] = (f32x4){0.f, 0.f, 0.f, 0.f};

    stage(0, 0);
    __syncthreads();

    const int nt = Kc >> 5;
    for (int t = 0; t < nt; ++t) {
        const int cur = t & 1;
        if (t + 1 < nt) stage(cur ^ 1, (t + 1) << 5);

        bf16x8 av[FM], bv[FN];
        #pragma unroll
        for (int i = 0; i < FM; ++i)
            av[i] = *(const bf16x8*)&At[cur][wm + i * 16 + l16][sc];
        #pragma unroll
        for (int j = 0; j < FN; ++j)
            bv[j] = *(const bf16x8*)&Bt[cur][wn + j * 16 + l16][sc];
        #pragma unroll
        for (int i = 0; i < FM; ++i)
            #pragma unroll
            for (int j = 0; j < FN; ++j)
                acc[i][j] = __builtin_amdgcn_mfma_f32_16x16x32_bf16(av[i], bv[j], acc[i][j], 0, 0, 0);
        __syncthreads();
    }

    float* Cf = (float*)Cp;
    __hip_bfloat16* Ch = (__hip_bfloat16*)Cp;
    const size_t cb0 = (size_t)slice * sC;
    #pragma unroll
    for (int i = 0; i < FM; ++i) {
        #pragma unroll
        for (int j = 0; j < FN; ++j) {
            const int row0 = m0 + wm + i * 16 + lq * 4;
            const int col  = n0 + wn + j * 16 + l16;
            #pragma unroll
            for (int r = 0; r < 4; ++r) {
                float v = acc[i][j][r] * scale;
                size_t idx = cb0 + (size_t)(row0 + r) * N + col;
                if (OUT_F32) Cf[idx] = v;
                else         Ch[idx] = __float2bfloat16(v);
            }
        }
    }
}

// Gb[b] = bf16( Gpart[b] + Gpart[4+b] ), bf16 partials, 8 elems/thread.
__global__ __launch_bounds__(256)
void reduce_kchunks(const unsigned short* __restrict__ part,
                    unsigned short* __restrict__ out)
{
    const size_t l = ((size_t)blockIdx.x * 256 + threadIdx.x) * 8;
    const size_t DD4 = (size_t)4 << 20;
    union { unsigned short h[8]; uint4 u; } a, b, o;
    a.u = *(const uint4*)(part + l);
    b.u = *(const uint4*)(part + l + DD4);
    #pragma unroll
    for (int j = 0; j < 8; ++j) {
        union { float f; unsigned int u; } fa, fb;
        fa.u = (unsigned int)a.h[j] << 16;
        fb.u = (unsigned int)b.h[j] << 16;
        o.h[j] = bf16bits(fa.f + fb.f);
    }
    *(uint4*)(out + l) = o.u;
}

// Tiled transpose + fp32->bf16 cast; batches b < nsb also emit row-major copy.
#define TP 64
__global__ __launch_bounds__(256)
void transpose_cast(const float* __restrict__ in, __hip_bfloat16* __restrict__ out,
                    __hip_bfloat16* __restrict__ straight, int nsb,
                    int R, int C, long inStride, long outStride)
{
    __shared__ __hip_bfloat16 t2[TP][TP + 4];
    const int b  = blockIdx.z;
    const int r0 = blockIdx.x * TP;
    const int c0 = blockIdx.y * TP;
    const float* inb = in + (size_t)b * inStride;
    __hip_bfloat16* outb = out + (size_t)b * outStride;
    __hip_bfloat16* stb  = straight + (size_t)b * inStride;
    const int t  = threadIdx.x;
    const int rr = t >> 4;
    const int c4 = (t & 15) * 4;
    #pragma unroll
    for (int p = 0; p < 4; ++p) {
        const int row = p * 16 + rr;
        float4 f = *(const float4*)&inb[(size_t)(r0 + row) * C + c0 + c4];
        union { __hip_bfloat16 h[4]; uint2 u; } s;
        s.h[0] = __float2bfloat16(f.x); s.h[1] = __float2bfloat16(f.y);
        s.h[2] = __float2bfloat16(f.z); s.h[3] = __float2bfloat16(f.w);
        t2[c4 + 0][row] = s.h[0];
        t2[c4 + 1][row] = s.h[1];
        t2[c4 + 2][row] = s.h[2];
        t2[c4 + 3][row] = s.h[3];
        if (b < nsb)
            *(uint2*)&stb[(size_t)(r0 + row) * C + c0 + c4] = s.u;
    }
    __syncthreads();
    #pragma unroll
    for (int p = 0; p < 4; ++p) {
        const int crow = p * 16 + rr;
        union { __hip_bfloat16 h[4]; uint2 u; } o;
        #pragma unroll
        for (int j = 0; j < 4; ++j) o.h[j] = t2[crow][c4 + j];
        *(uint2*)&outb[(size_t)(c0 + crow) * R + r0 + c4] = o.u;
    }
}

__global__ __launch_bounds__(256)
void cast_f32_bf16(const float* __restrict__ in, __hip_bfloat16* __restrict__ out, int n)
{
    const int i = (blockIdx.x * 256 + threadIdx.x) << 2;
    if (i >= n) return;
    float4 f = *(const float4*)(in + i);
    union { __hip_bfloat16 h[4]; uint2 u; } t;
    t.h[0] = __float2bfloat16(f.x); t.h[1] = __float2bfloat16(f.y);
    t.h[2] = __float2bfloat16(f.z); t.h[3] = __float2bfloat16(f.w);
    *(uint2*)(out + i) = t.u;
}

extern "C" void kernel_launch(void* const* d_in, const int* in_sizes, int n_in,
                              void* d_out, int out_size, void* d_ws, size_t ws_size,
                              hipStream_t stream)
{
    const int Bz = 4, T = 4096, D = 1024;
    const float gamma = 32.0f;  // sqrt(1024)

    const float* x  = (const float*)d_in[0];
    const float* wq = (const float*)d_in[1];
    const float* wk = (const float*)d_in[2];
    const float* wv = (const float*)d_in[3];
    float* y = (float*)d_out;

    // workspace layout (32 MB total)
    unsigned char* p = (unsigned char*)d_ws;
    const size_t DD = (size_t)D * D;
    __hip_bfloat16* Gb  = (__hip_bfloat16*)p; p += Bz * DD * 2;   //  8 MB
    __hip_bfloat16* Hb  = (__hip_bfloat16*)p; p += Bz * DD * 2;   //  8 MB
    __hip_bfloat16* PTb = (__hip_bfloat16*)p; p += Bz * DD * 2;   //  8 MB
    __hip_bfloat16* wqb = (__hip_bfloat16*)p; p += DD * 2;        //  2 MB
    __hip_bfloat16* wkb = (__hip_bfloat16*)p; p += DD * 2;        //  2 MB
    __hip_bfloat16* wvT = (__hip_bfloat16*)p; p += DD * 2;        //  2 MB
    __hip_bfloat16* C0b = (__hip_bfloat16*)p; p += DD * 2;        //  2 MB
    __hip_bfloat16* Gpart = Hb;                                   // 16 MB (Hb+PTb)
    __hip_bfloat16* xb23  = Gb;                                   // 16 MB (Gb+Hb)

    __hip_bfloat16* xbT  = (__hip_bfloat16*)d_out;                                  // [0,32M)
    __hip_bfloat16* xb01 = (__hip_bfloat16*)((unsigned char*)d_out + ((size_t)32 << 20)); // [32,48M)

    dim3 blk(256);

    // weight casts / transposes; x transpose fuses the bf16 row-major copy of b0,b1
    cast_f32_bf16<<<dim3((int)(DD / 1024)), blk, 0, stream>>>(wq, wqb, (int)DD);
    cast_f32_bf16<<<dim3((int)(DD / 1024)), blk, 0, stream>>>(wk, wkb, (int)DD);
    transpose_cast<<<dim3(D / TP, D / TP, 1), blk, 0, stream>>>(
        wv, wvT, wvT, 0, D, D, 0, 0);
    transpose_cast<<<dim3(T / TP, D / TP, Bz), blk, 0, stream>>>(
        x, xbT, xb01, 2, T, D, (long)T * D, (long)D * T);

    // C0 = w_q w_k^T                      : NT(wq, wk)       64x128, MODE 0
    gemm_nt<64, 128, 0, false><<<dim3(D / 128, D / 64, 1), blk, 0, stream>>>(
        wqb, wkb, C0b, D, D, D, D, 0, 0, 0, 1, 1.0f);
    // Gpart[kc*4+b] = xbT[b][:, kc*2048:+2048] x same : split-K=2, 8-wave pipeline
    // 256 blocks (8 slices x 32 tiles), slice->XCD pin (4 MB L2-resident panels)
    gemm8<1, false><<<dim3(256), dim3(512), 0, stream>>>(
        xbT, xbT, Gpart, D, T / 2, T, T, (long)D * T, (long)D * T, (long)DD, Bz, 8, 1.0f);
    // Gb = bf16(Gpart[b] + Gpart[4+b])
    reduce_kchunks<<<dim3((int)(Bz * DD / 2048)), blk, 0, stream>>>(
        (const unsigned short*)Gpart, (unsigned short*)Gb);
    // H_b = C0 G_b (G symmetric)          : NT(C0, G)        64x128, batch->XCD pin
    gemm_nt<64, 128, 2, false><<<dim3(D / 128, D / 64, Bz), blk, 0, stream>>>(
        C0b, Gb, Hb, D, D, D, D, 0, (long)DD, (long)DD, Bz, 1.0f);
    // P_b^T = gamma * w_v^T H_b^T         : NT(wvT, H)       64x128, batch->XCD pin
    gemm_nt<64, 128, 2, false><<<dim3(D / 128, D / 64, Bz), blk, 0, stream>>>(
        wvT, Hb, PTb, D, D, D, D, 0, (long)DD, (long)DD, Bz, gamma);

    // xb23 = bf16(x[b2,b3]) into dead Gb+Hb slots (stream-ordered after P GEMM)
    cast_f32_bf16<<<dim3((int)(2 * (size_t)T * D / 1024)), blk, 0, stream>>>(
        x + (size_t)2 * T * D, xb23, (int)(2 * (size_t)T * D));

    // y_b = x_b P_b : NT(xb, P^T), fp32 out, 8-wave pipeline, 256 blocks each
    // A: batches 0,1 read xb01 @ d_out[32,48M), write y @ d_out[0,32M)
    gemm8<2, true><<<dim3(256), dim3(512), 0, stream>>>(
        xb01, PTb, y, D, D, D, D, (long)T * D, (long)DD, (long)T * D, 2, 8, 1.0f);
    // B: batches 2,3 read xb23 @ ws, write y @ d_out[32,64M) (xb01 dead)
    gemm8<2, true><<<dim3(256), dim3(512), 0, stream>>>(
        xb23, PTb + 2 * DD, y + (size_t)2 * T * D, D, D, D, D,
        (long)T * D, (long)DD, (long)T * D, 2, 8, 1.0f);
}

// Round 7
// 271.379 us; speedup vs baseline: 1.3562x; 1.0154x over previous
//
#include <hip/hip_runtime.h>
#include <hip/hip_bf16.h>

// y = x @ P,  P = gamma * (w_q w_k^T) (x^T x) w_v      (no softmax => associativity)
// All GEMMs: NT form  C[m][n] = scale * sum_k A[m][k] * B[n][k], all operands bf16.
// Big GEMMs (G, y): gemm8 — 256x128 tile, 8 waves, BK=64, triple-buffered LDS,
//   2 phases per K-tile (T3 fine interleave: ds_read || stage-half || barrier ||
//   lgkm(0) || setprio MFMA x16 || barrier), counted vmcnt(6) once per tile (T4),
//   T2 slot-XOR swizzle (global-source side), XCD-pinned grids (T1).
// Small GEMMs (C0, H, P): proven 2-phase 64x128 kernel.
//
// Buffer choreography (stream-ordered dispatches; liveness checked per dispatch):
//   ws: S0(8M) S1(8M) S2(8M) | wqb(2M) wkb(2M) wvT(2M) C0b(2M)
//   transpose: xbT -> d_out[0,32M); xb01 -> d_out[32,48M); xb23 -> S0+S1
//   G GEMM:   reads xbT, writes Gpart -> d_out[48,64M)
//   reduce:   reads Gpart, writes Gb -> S2                 (xbT dead)
//   H GEMM:   reads C0b,Gb(S2), writes Hb -> d_out[0,8M)
//   P GEMM:   reads wvT,Hb, writes PTb -> S2               (Gb dead)
//   y-A: reads xb01(d_out[32,48M)), PTb(S2) -> y d_out[0,32M)   (Hb dead)
//   y-B: reads xb23(S0+S1), PTb+2DD      -> y d_out[32,64M)     (xb01,Gpart dead)

typedef __attribute__((ext_vector_type(8))) short bf16x8;   // 8 x bf16 (4 VGPRs)
typedef __attribute__((ext_vector_type(4))) float f32x4;    // 4 x fp32 accum

__device__ __forceinline__ unsigned short bf16bits(float f) {
    union { __hip_bfloat16 b; unsigned short s; } r;
    r.b = __float2bfloat16(f);
    return r.s;
}

// async global->LDS, 16B per lane; LDS dest must be wave-uniform base + lane*16.
__device__ __forceinline__ void gload16(const void* g, void* l) {
    __builtin_amdgcn_global_load_lds((__attribute__((address_space(1))) void*)g,
                                     (__attribute__((address_space(3))) void*)l,
                                     16, 0, 0);
}

// ---------------------------------------------------------------------------
// gemm8: BM=256 x BN=128, BK=64, 512 threads (8 waves, 4m x 2n), per-wave 64x64.
// Per K-tile, 2 phases (kk=0,1). Phase template (m201-faithful):
//   8 ds_read_b128 (swizzled) ; stage 3 gloads of tile t+2 ;
//   [phase1 only: s_waitcnt vmcnt(6) -- tile t+1 landed, t+2 in flight]
//   s_barrier ; lgkmcnt(0) ; sched_barrier ; setprio(1) 16 MFMA setprio(0) ; s_barrier
// Race-freedom: all waves pass tile-(t-1) closing barrier (their buf[(t-1)%3]
// reads done via lgkm(0)) before any wave stages tile t+2 into the same buffer.
// Swizzle: LDS slot s of row r holds global cols (s^(r&7))*8 (dest linear,
// source-permuted, rule #21); reads use the same XOR. Measured 0 conflicts.
// MODE 1: slice = h&7 (slice->XCD pin). MODE 2: batch = (h&7)%nb, contiguous
// m-chunks per XCD. Grid must be 256 blocks (1 block/CU, 8 waves).
// ---------------------------------------------------------------------------
template<int MODE, bool OUT_F32>
__global__ __launch_bounds__(512, 2)
void gemm8(const __hip_bfloat16* __restrict__ Ap, const __hip_bfloat16* __restrict__ Bp,
           void* __restrict__ Cp, int N, int Kc, int ldA, int ldB,
           long sA, long sB, long sC, int nb, int tnc, float scale)
{
    constexpr int BM = 256, BN = 128, BK = 64;
    __shared__ __hip_bfloat16 lds[3][(BM + BN) * BK];   // 3 x 48KB = 144 KB

    const int h = blockIdx.x;
    int slice, tile;
    if (MODE == 1) { slice = h & 7; tile = h >> 3; }
    else {
        const int xcd = h & 7;
        slice = xcd % nb;
        tile  = (xcd / nb) * ((int)gridDim.x >> 3) + (h >> 3);
    }
    const int batch = slice % nb, kc = slice / nb;
    const int n0 = (tile % tnc) * BN;
    const int m0 = (tile / tnc) * BM;

    const int tid  = threadIdx.x;
    const int lane = tid & 63;
    const int w    = tid >> 6;
    const int wm = (w >> 1) * 64, wn = (w & 1) * 64;
    const int l16 = lane & 15, lq = lane >> 4;

    // staging geometry: wave-instr covers 8 rows x 128B; source col swizzled
    const int srow = lane >> 3;                  // 0..7 within 8-row group
    const int scol = ((lane & 7) ^ srow) << 3;   // swizzled source col (elems)
    const int soff = w * 512 + lane * 8;         // LDS elem base (i=0)

    const __hip_bfloat16* Ab = Ap + (size_t)batch * sA + (size_t)kc * Kc;
    const __hip_bfloat16* Bb = Bp + (size_t)batch * sB + (size_t)kc * Kc;

    const int nt = Kc >> 6;
    // stage half of tile t (3 gloads) into lds[t%3]; k0 clamped for tail
    auto stageH = [&](int t, int half) {
        const int k0 = (t < nt ? t : nt - 1) << 6;
        __hip_bfloat16* L = &lds[t % 3][0];
        if (half == 0) {
            gload16(Ab + (size_t)(m0 +   0 + w * 8 + srow) * ldA + k0 + scol, L + 0 * 4096 + soff);
            gload16(Ab + (size_t)(m0 +  64 + w * 8 + srow) * ldA + k0 + scol, L + 1 * 4096 + soff);
            gload16(Bb + (size_t)(n0 +   0 + w * 8 + srow) * ldB + k0 + scol, L + BM * BK + 0 * 4096 + soff);
        } else {
            gload16(Ab + (size_t)(m0 + 128 + w * 8 + srow) * ldA + k0 + scol, L + 2 * 4096 + soff);
            gload16(Ab + (size_t)(m0 + 192 + w * 8 + srow) * ldA + k0 + scol, L + 3 * 4096 + soff);
            gload16(Bb + (size_t)(n0 +  64 + w * 8 + srow) * ldB + k0 + scol, L + BM * BK + 1 * 4096 + soff);
        }
    };

    f32x4 acc[4][4];
    #pragma unroll
    for (int i = 0; i < 4; ++i)
        #pragma unroll
        for (int j = 0; j < 4; ++j)
            acc[i][j] = (f32x4){0.f, 0.f, 0.f, 0.f};

    stageH(0, 0); stageH(0, 1);
    stageH(1, 0); stageH(1, 1);                 // 12 loads/wave in flight
    asm volatile("s_waitcnt vmcnt(6)" ::: "memory");   // tile 0 landed
    __builtin_amdgcn_s_barrier();
    asm volatile("" ::: "memory");

    for (int t = 0; t < nt; ++t) {
        const __hip_bfloat16* LA = &lds[t % 3][0];
        const __hip_bfloat16* LB = LA + BM * BK;
        #pragma unroll
        for (int kk = 0; kk < 2; ++kk) {
            const int sc = ((kk * 4 + lq) ^ (l16 & 7)) << 3;   // swizzled read col
            bf16x8 av[4], bv[4];
            #pragma unroll
            for (int i = 0; i < 4; ++i)
                av[i] = *(const bf16x8*)&LA[(wm + i * 16 + l16) * BK + sc];
            #pragma unroll
            for (int j = 0; j < 4; ++j)
                bv[j] = *(const bf16x8*)&LB[(wn + j * 16 + l16) * BK + sc];
            stageH(t + 2, kk);                  // 3 prefetch loads this phase
            if (kk == 1)                        // once per tile: t+1 landed
                asm volatile("s_waitcnt vmcnt(6)" ::: "memory");
            __builtin_amdgcn_s_barrier();
            asm volatile("s_waitcnt lgkmcnt(0)" ::: "memory");
            __builtin_amdgcn_sched_barrier(0);  // rule #18: pin MFMA below waits
            __builtin_amdgcn_s_setprio(1);
            #pragma unroll
            for (int i = 0; i < 4; ++i)
                #pragma unroll
                for (int j = 0; j < 4; ++j)
                    acc[i][j] = __builtin_amdgcn_mfma_f32_16x16x32_bf16(av[i], bv[j], acc[i][j], 0, 0, 0);
            __builtin_amdgcn_s_setprio(0);
            __builtin_amdgcn_s_barrier();
            asm volatile("" ::: "memory");
        }
    }
    asm volatile("s_waitcnt vmcnt(0)" ::: "memory");   // drain tail DMA

    // epilogue: C/D layout col=lane&15, row=(lane>>4)*4+reg (m89/m91-verified)
    float* Cf = (float*)Cp;
    __hip_bfloat16* Ch = (__hip_bfloat16*)Cp;
    const size_t cb0 = (size_t)slice * sC;
    #pragma unroll
    for (int i = 0; i < 4; ++i) {
        #pragma unroll
        for (int j = 0; j < 4; ++j) {
            const int row0 = m0 + wm + i * 16 + lq * 4;
            const int col  = n0 + wn + j * 16 + l16;
            #pragma unroll
            for (int r = 0; r < 4; ++r) {
                float v = acc[i][j][r] * scale;
                size_t idx = cb0 + (size_t)(row0 + r) * N + col;
                if (OUT_F32) Cf[idx] = v;
                else         Ch[idx] = __float2bfloat16(v);
            }
        }
    }
}

// ---------------------------------------------------------------------------
// 2-phase 64x128 kernel (proven) for the small D^3 chain GEMMs (C0, H, P).
// ---------------------------------------------------------------------------
template<int TM, int TN, int MODE, bool OUT_F32>
__global__ __launch_bounds__(256)
void gemm_nt(const __hip_bfloat16* __restrict__ Ap, const __hip_bfloat16* __restrict__ Bp,
             void* __restrict__ Cp, int N, int Kc, int ldA, int ldB,
             long sA, long sB, long sC, int nb, float scale)
{
    constexpr int FM = TM / 32;
    constexpr int FN = TN / 32;

    __shared__ __hip_bfloat16 At[2][TM][32];
    __shared__ __hip_bfloat16 Bt[2][TN][32];

    const int gx = (int)gridDim.x, gy = (int)gridDim.y, gz = (int)gridDim.z;
    int slice, tile;
    if (MODE == 0) {
        slice = blockIdx.z;
        int wg = blockIdx.y * gx + blockIdx.x;
        const int cpx = (gx * gy) >> 3;
        tile = (wg & 7) * cpx + (wg >> 3);
    } else {
        const int h = ((int)blockIdx.z * gy + (int)blockIdx.y) * gx + (int)blockIdx.x;
        const int xcd = h & 7, k = h >> 3;
        if (MODE == 1) {
            const int SL = gz >> 3;
            slice = xcd + 8 * (k % SL);
            tile  = k / SL;
        } else {
            slice = xcd % gz;
            tile  = (xcd / gz) * ((gx * gy * gz) >> 3) + k;
        }
    }
    const int batch = slice % nb;
    const int kc    = slice / nb;
    const int n0 = (tile % gx) * TN;
    const int m0 = (tile / gx) * TM;

    const int tid  = threadIdx.x;
    const int lane = tid & 63;
    const int wave = tid >> 6;
    const int wm = (wave & 1) * (TM / 2);
    const int wn = (wave >> 1) * (TN / 2);
    const int l16 = lane & 15;
    const int lq  = lane >> 4;

    const int aoff = wave * (TM * 8) + lane * 8;
    const int boff = wave * (TN * 8) + lane * 8;
    const int arow = aoff >> 5, brow = boff >> 5;
    const int acs = (((aoff >> 3) & 3) ^ ((aoff >> 6) & 3)) << 3;
    const int bcs = (((boff >> 3) & 3) ^ ((boff >> 6) & 3)) << 3;
    const int sc = (lq ^ ((l16 >> 1) & 3)) << 3;

    const __hip_bfloat16* Ab = Ap + (size_t)batch * sA + (size_t)kc * Kc;
    const __hip_bfloat16* Bb = Bp + (size_t)batch * sB + (size_t)kc * Kc;

    auto stage = [&](int buf, int k0) {
        #pragma unroll
        for (int i = 0; i < TM / 64; ++i)
            gload16(Ab + (size_t)(m0 + arow + i * 16) * ldA + k0 + acs,
                    &At[buf][0][0] + aoff + i * 512);
        #pragma unroll
        for (int i = 0; i < TN / 64; ++i)
            gload16(Bb + (size_t)(n0 + brow + i * 16) * ldB + k0 + bcs,
                    &Bt[buf][0][0] + boff + i * 512);
    };

    f32x4 acc[FM][FN];
    #pragma unroll
    for (int i = 0; i < FM; ++i)
        #pragma unroll
        for (int j = 0; j < FN; ++j)
            acc[i][j] = (f32x4){0.f, 0.f, 0.f, 0.f};

    stage(0, 0);
    __syncthreads();

    const int nt = Kc >> 5;
    for (int t = 0; t < nt; ++t) {
        const int cur = t & 1;
        if (t + 1 < nt) stage(cur ^ 1, (t + 1) << 5);

        bf16x8 av[FM], bv[FN];
        #pragma unroll
        for (int i = 0; i < FM; ++i)
            av[i] = *(const bf16x8*)&At[cur][wm + i * 16 + l16][sc];
        #pragma unroll
        for (int j = 0; j < FN; ++j)
            bv[j] = *(const bf16x8*)&Bt[cur][wn + j * 16 + l16][sc];
        #pragma unroll
        for (int i = 0; i < FM; ++i)
            #pragma unroll
            for (int j = 0; j < FN; ++j)
                acc[i][j] = __builtin_amdgcn_mfma_f32_16x16x32_bf16(av[i], bv[j], acc[i][j], 0, 0, 0);
        __syncthreads();
    }

    float* Cf = (float*)Cp;
    __hip_bfloat16* Ch = (__hip_bfloat16*)Cp;
    const size_t cb0 = (size_t)slice * sC;
    #pragma unroll
    for (int i = 0; i < FM; ++i) {
        #pragma unroll
        for (int j = 0; j < FN; ++j) {
            const int row0 = m0 + wm + i * 16 + lq * 4;
            const int col  = n0 + wn + j * 16 + l16;
            #pragma unroll
            for (int r = 0; r < 4; ++r) {
                float v = acc[i][j][r] * scale;
                size_t idx = cb0 + (size_t)(row0 + r) * N + col;
                if (OUT_F32) Cf[idx] = v;
                else         Ch[idx] = __float2bfloat16(v);
            }
        }
    }
}

// Gb[b] = bf16( Gpart[b] + Gpart[4+b] ), bf16 partials, 8 elems/thread.
__global__ __launch_bounds__(256)
void reduce_kchunks(const unsigned short* __restrict__ part,
                    unsigned short* __restrict__ out)
{
    const size_t l = ((size_t)blockIdx.x * 256 + threadIdx.x) * 8;
    const size_t DD4 = (size_t)4 << 20;
    union { unsigned short h[8]; uint4 u; } a, b, o;
    a.u = *(const uint4*)(part + l);
    b.u = *(const uint4*)(part + l + DD4);
    #pragma unroll
    for (int j = 0; j < 8; ++j) {
        union { float f; unsigned int u; } fa, fb;
        fa.u = (unsigned int)a.h[j] << 16;
        fb.u = (unsigned int)b.h[j] << 16;
        o.h[j] = bf16bits(fa.f + fb.f);
    }
    *(uint4*)(out + l) = o.u;
}

// Tiled transpose + fp32->bf16 cast: in (R x C) fp32 row-major -> out (C x R) bf16.
// Batches b < nsb also emit a straight row-major bf16 copy: b<2 -> s01, else s23.
#define TP 64
__global__ __launch_bounds__(256)
void transpose_cast(const float* __restrict__ in, __hip_bfloat16* __restrict__ out,
                    __hip_bfloat16* __restrict__ s01, __hip_bfloat16* __restrict__ s23,
                    int nsb, int R, int C, long inStride, long outStride)
{
    __shared__ __hip_bfloat16 t2[TP][TP + 4];
    const int b  = blockIdx.z;
    const int r0 = blockIdx.x * TP;
    const int c0 = blockIdx.y * TP;
    const float* inb = in + (size_t)b * inStride;
    __hip_bfloat16* outb = out + (size_t)b * outStride;
    __hip_bfloat16* stb  = (b < 2) ? s01 + (size_t)b * inStride
                                   : s23 + (size_t)(b - 2) * inStride;
    const int t  = threadIdx.x;
    const int rr = t >> 4;
    const int c4 = (t & 15) * 4;
    #pragma unroll
    for (int p = 0; p < 4; ++p) {
        const int row = p * 16 + rr;
        float4 f = *(const float4*)&inb[(size_t)(r0 + row) * C + c0 + c4];
        union { __hip_bfloat16 h[4]; uint2 u; } s;
        s.h[0] = __float2bfloat16(f.x); s.h[1] = __float2bfloat16(f.y);
        s.h[2] = __float2bfloat16(f.z); s.h[3] = __float2bfloat16(f.w);
        t2[c4 + 0][row] = s.h[0];
        t2[c4 + 1][row] = s.h[1];
        t2[c4 + 2][row] = s.h[2];
        t2[c4 + 3][row] = s.h[3];
        if (b < nsb)
            *(uint2*)&stb[(size_t)(r0 + row) * C + c0 + c4] = s.u;
    }
    __syncthreads();
    #pragma unroll
    for (int p = 0; p < 4; ++p) {
        const int crow = p * 16 + rr;
        union { __hip_bfloat16 h[4]; uint2 u; } o;
        #pragma unroll
        for (int j = 0; j < 4; ++j) o.h[j] = t2[crow][c4 + j];
        *(uint2*)&outb[(size_t)(c0 + crow) * R + r0 + c4] = o.u;
    }
}

// wq and wk cast in one dispatch (outputs contiguous: wqb then wkb).
__global__ __launch_bounds__(256)
void cast_qk(const float* __restrict__ wq, const float* __restrict__ wk,
             __hip_bfloat16* __restrict__ out, int n)
{
    const float* src = blockIdx.y ? wk : wq;
    __hip_bfloat16* dst = out + (size_t)blockIdx.y * n;
    const int i = (blockIdx.x * 256 + threadIdx.x) << 2;
    if (i >= n) return;
    float4 f = *(const float4*)(src + i);
    union { __hip_bfloat16 h[4]; uint2 u; } t;
    t.h[0] = __float2bfloat16(f.x); t.h[1] = __float2bfloat16(f.y);
    t.h[2] = __float2bfloat16(f.z); t.h[3] = __float2bfloat16(f.w);
    *(uint2*)(dst + i) = t.u;
}

extern "C" void kernel_launch(void* const* d_in, const int* in_sizes, int n_in,
                              void* d_out, int out_size, void* d_ws, size_t ws_size,
                              hipStream_t stream)
{
    const int Bz = 4, T = 4096, D = 1024;
    const float gamma = 32.0f;  // sqrt(1024)

    const float* x  = (const float*)d_in[0];
    const float* wq = (const float*)d_in[1];
    const float* wk = (const float*)d_in[2];
    const float* wv = (const float*)d_in[3];
    float* y = (float*)d_out;

    // workspace layout (32 MB total)
    unsigned char* p = (unsigned char*)d_ws;
    const size_t DD = (size_t)D * D;
    __hip_bfloat16* S0  = (__hip_bfloat16*)p;                      // 8 MB (xb23 lo)
    __hip_bfloat16* S2  = (__hip_bfloat16*)(p + ((size_t)16 << 20)); // 8 MB (Gb -> PTb)
    __hip_bfloat16* wqb = (__hip_bfloat16*)(p + ((size_t)24 << 20)); // 2 MB
    __hip_bfloat16* wkb = wqb + DD;                                // 2 MB
    __hip_bfloat16* wvT = wkb + DD;                                // 2 MB
    __hip_bfloat16* C0b = wvT + DD;                                // 2 MB
    __hip_bfloat16* xb23 = S0;                                     // 16 MB (S0+S1)

    __hip_bfloat16* xbT   = (__hip_bfloat16*)d_out;                                    // [0,32M)
    __hip_bfloat16* xb01  = (__hip_bfloat16*)((unsigned char*)d_out + ((size_t)32 << 20)); // [32,48M)
    __hip_bfloat16* Gpart = (__hip_bfloat16*)((unsigned char*)d_out + ((size_t)48 << 20)); // [48,64M)
    __hip_bfloat16* Hb    = (__hip_bfloat16*)d_out;                                    // [0,8M) after G
    __hip_bfloat16* Gb    = S2;
    __hip_bfloat16* PTb   = S2;                                    // overwrites Gb after H

    dim3 blk(256);

    // weight casts / transposes; x transpose emits all 4 straight bf16 copies
    cast_qk<<<dim3((int)(DD / 1024), 2), blk, 0, stream>>>(wq, wk, wqb, (int)DD);
    transpose_cast<<<dim3(D / TP, D / TP, 1), blk, 0, stream>>>(
        wv, wvT, wvT, wvT, 0, D, D, 0, 0);
    transpose_cast<<<dim3(T / TP, D / TP, Bz), blk, 0, stream>>>(
        x, xbT, xb01, xb23, 4, T, D, (long)T * D, (long)D * T);

    // C0 = w_q w_k^T                      : NT(wq, wk)       64x128, MODE 0
    gemm_nt<64, 128, 0, false><<<dim3(D / 128, D / 64, 1), blk, 0, stream>>>(
        wqb, wkb, C0b, D, D, D, D, 0, 0, 0, 1, 1.0f);
    // Gpart[kc*4+b] = xbT[b][:, kc*2048:+2048] x same : split-K=2, 8-wave pipeline
    // 256 blocks (8 slices x 32 tiles), slice->XCD pin (4 MB L2-resident panels)
    gemm8<1, false><<<dim3(256), dim3(512), 0, stream>>>(
        xbT, xbT, Gpart, D, T / 2, T, T, (long)D * T, (long)D * T, (long)DD, Bz, 8, 1.0f);
    // Gb = bf16(Gpart[b] + Gpart[4+b])   -> S2
    reduce_kchunks<<<dim3((int)(Bz * DD / 2048)), blk, 0, stream>>>(
        (const unsigned short*)Gpart, (unsigned short*)Gb);
    // H_b = C0 G_b (G symmetric)          : NT(C0, G)        64x128, batch->XCD pin
    gemm_nt<64, 128, 2, false><<<dim3(D / 128, D / 64, Bz), blk, 0, stream>>>(
        C0b, Gb, Hb, D, D, D, D, 0, (long)DD, (long)DD, Bz, 1.0f);
    // P_b^T = gamma * w_v^T H_b^T         : NT(wvT, H)       64x128, batch->XCD pin
    gemm_nt<64, 128, 2, false><<<dim3(D / 128, D / 64, Bz), blk, 0, stream>>>(
        wvT, Hb, PTb, D, D, D, D, 0, (long)DD, (long)DD, Bz, gamma);

    // y_b = x_b P_b : NT(xb, P^T), fp32 out, 8-wave pipeline, 256 blocks each
    // A: batches 0,1 read xb01 @ d_out[32,48M), write y @ d_out[0,32M)
    gemm8<2, true><<<dim3(256), dim3(512), 0, stream>>>(
        xb01, PTb, y, D, D, D, D, (long)T * D, (long)DD, (long)T * D, 2, 8, 1.0f);
    // B: batches 2,3 read xb23 @ ws, write y @ d_out[32,64M) (xb01, Gpart dead)
    gemm8<2, true><<<dim3(256), dim3(512), 0, stream>>>(
        xb23, PTb + 2 * DD, y + (size_t)2 * T * D, D, D, D, D,
        (long)T * D, (long)DD, (long)T * D, 2, 8, 1.0f);
}